// Round 3
// baseline (1326.362 us; speedup 1.0000x reference)
//
#include <hip/hip_runtime.h>
#include <cstdint>
#include <cstddef>

#define N_NODES 20000
#define N_EDGES 400000

// ---------- bf16 helpers (manual, bit-exact) ----------
__device__ __forceinline__ float bf2f(unsigned short u) {
    return __uint_as_float(((unsigned int)u) << 16);
}
__device__ __forceinline__ unsigned short f2bf(float f) {
    unsigned int x = __float_as_uint(f);
    unsigned int lsb = (x >> 16) & 1u;
    x += 0x7fffu + lsb;  // round-to-nearest-even
    return (unsigned short)(x >> 16);
}

// ---------- internal (templated) scalar/vector load-store ----------
__device__ __forceinline__ float ld1(const float* p) { return *p; }
__device__ __forceinline__ float ld1(const unsigned short* p) { return bf2f(*p); }
__device__ __forceinline__ void st1(float* p, float v) { *p = v; }
__device__ __forceinline__ void st1(unsigned short* p, float v) { *p = f2bf(v); }
__device__ __forceinline__ void load4(const float* p, float4& v) {
    v = *(const float4*)p;
}
__device__ __forceinline__ void load4(const unsigned short* p, float4& v) {
    ushort4 u = *(const ushort4*)p;
    v = make_float4(bf2f(u.x), bf2f(u.y), bf2f(u.z), bf2f(u.w));
}

// ---------- flag-aware loads for harness float tensors (bf16 or fp32) ----------
__device__ __forceinline__ float ldF(const void* p, size_t i, bool bf) {
    return bf ? bf2f(((const unsigned short*)p)[i]) : ((const float*)p)[i];
}
__device__ __forceinline__ void ld4F(const void* p, size_t i, bool bf, float4& v) {
    if (bf) {
        ushort4 u = *(const ushort4*)(((const unsigned short*)p) + i);
        v = make_float4(bf2f(u.x), bf2f(u.y), bf2f(u.z), bf2f(u.w));
    } else {
        v = *(const float4*)(((const float*)p) + i);
    }
}

// ---------- dtype detection: bf16 vs fp32, from x's bit patterns ----------
// Low ushort of each 32-bit word: bf16 => N(0,1) sample, exponent in [110,135]
// w.p. ~1. fp32 => low mantissa bits, exponent field uniform => ~10% in range.
__global__ void k_detect(const unsigned int* __restrict__ xw, int* __restrict__ flag) {
    if (threadIdx.x != 0 || blockIdx.x != 0) return;
    int cnt = 0;
    for (int i = 0; i < 256; ++i) {
        unsigned short lo = (unsigned short)(xw[i] & 0xffffu);
        int e = (lo >> 7) & 0xff;
        if (e >= 110 && e <= 135) cnt++;
    }
    *flag = (cnt >= 128) ? 1 : 0;  // 1 = bf16
}

// ---------- canonicalize edge_index (handles int32 or raw-int64 layouts) ----------
__global__ void k_canon(const int* __restrict__ raw, int* __restrict__ src32,
                        int* __restrict__ dst32) {
    __shared__ int is64;
    if (threadIdx.x == 0) {
        int z = 1;
        // if data is int64 (values >=0, < 2^31), every odd int32 word is 0
        for (int i = 1; i < 512; i += 2)
            if (raw[i] != 0) { z = 0; break; }
        is64 = z;
    }
    __syncthreads();
    int e = blockIdx.x * blockDim.x + threadIdx.x;
    if (e >= N_EDGES) return;
    if (is64) {
        src32[e] = raw[2 * e];
        dst32[e] = raw[2 * (N_EDGES + e)];
    } else {
        src32[e] = raw[e];
        dst32[e] = raw[N_EDGES + e];
    }
}

// ---------- precompute: degree + edge counts ----------
__global__ void k_deg(const int* __restrict__ src, const int* __restrict__ dst,
                      const void* __restrict__ ew, const int* __restrict__ flagp,
                      float* __restrict__ deg, int* __restrict__ counts) {
    bool bf = (*flagp != 0);
    int e = blockIdx.x * blockDim.x + threadIdx.x;
    if (e >= N_EDGES) return;
    int d = dst[e];
    atomicAdd(&deg[d], ldF(ew, e, bf));
    atomicAdd(&counts[d], 1);
}

__global__ void k_dinv(const float* __restrict__ deg, float* __restrict__ dinv,
                       float* __restrict__ selfnorm) {
    int i = blockIdx.x * blockDim.x + threadIdx.x;
    if (i >= N_NODES) return;
    float d = deg[i] + 1.0f;  // + self-loop weight 1
    float r = rsqrtf(d);      // d >= 1 always
    dinv[i] = r;
    selfnorm[i] = r * r;
}

// ---------- single-block exclusive scan of counts -> rowptr ----------
__global__ void k_scan(const int* __restrict__ counts, int* __restrict__ rowptr) {
    __shared__ int s[1024];
    const int T = 1024, CH = 20;  // 1024*20 >= 20000
    int t = threadIdx.x;
    int base = t * CH;
    int local = 0;
    for (int j = 0; j < CH; ++j) {
        int idx = base + j;
        if (idx < N_NODES) local += counts[idx];
    }
    s[t] = local;
    __syncthreads();
    for (int off = 1; off < T; off <<= 1) {
        int v = (t >= off) ? s[t - off] : 0;
        __syncthreads();
        s[t] += v;
        __syncthreads();
    }
    int run = (t > 0) ? s[t - 1] : 0;  // exclusive prefix of this chunk
    for (int j = 0; j < CH; ++j) {
        int idx = base + j;
        if (idx < N_NODES) { rowptr[idx] = run; run += counts[idx]; }
    }
    if (t == T - 1) rowptr[N_NODES] = s[T - 1];
}

// ---------- scatter edges into CSR-by-dst with per-edge norm ----------
__global__ void k_csr(const int* __restrict__ src, const int* __restrict__ dst,
                      const void* __restrict__ ew, const int* __restrict__ flagp,
                      const float* __restrict__ dinv, const int* __restrict__ rowptr,
                      int* __restrict__ fill, int* __restrict__ csr_src,
                      float* __restrict__ csr_norm) {
    bool bf = (*flagp != 0);
    int e = blockIdx.x * blockDim.x + threadIdx.x;
    if (e >= N_EDGES) return;
    int s = src[e], d = dst[e];
    int p = rowptr[d] + atomicAdd(&fill[d], 1);
    csr_src[p] = s;
    csr_norm[p] = dinv[s] * ldF(ew, e, bf) * dinv[d];
}

// ---------- input cast -> internal dtype ----------
template <typename TOUT>
__global__ void k_cast_in(const void* __restrict__ x, const int* __restrict__ flagp,
                          TOUT* __restrict__ out, int n) {
    bool bf = (*flagp != 0);
    int i = blockIdx.x * blockDim.x + threadIdx.x;
    if (i < n) st1(&out[i], ldF(x, i, bf));
}

// ---------- tiled GEMM: C[M,N] = A[M,K](internal) * B[K,N](harness float) ----------
// BM=BN=64, BK=16, 256 threads, 4x4 micro-tile per thread.
template <typename TA, typename TC>
__global__ __launch_bounds__(256) void k_gemm(const TA* __restrict__ A,
                                              const void* __restrict__ B,
                                              const int* __restrict__ flagp,
                                              TC* __restrict__ C,
                                              int M, int K, int N) {
    const int BM = 64, BN = 64, BK = 16;
    __shared__ float As[BK][BM + 1];
    __shared__ float Bs[BK][BN];
    bool bf = (*flagp != 0);
    int tid = threadIdx.x;
    int tx = tid & 15, ty = tid >> 4;
    int row0 = blockIdx.x * BM;
    int col0 = blockIdx.y * BN;
    float acc[4][4] = {};

    int ar = tid >> 2;         // 0..63
    int ac0 = (tid & 3) << 2;  // 0,4,8,12
    int br = tid >> 4;         // 0..15
    int bc0 = (tid & 15) << 2; // 0..60

    for (int k0 = 0; k0 < K; k0 += BK) {
        int arow = row0 + ar;
        if (arow < M) {
            float4 av;
            load4(&A[(size_t)arow * K + k0 + ac0], av);
            As[ac0 + 0][ar] = av.x; As[ac0 + 1][ar] = av.y;
            As[ac0 + 2][ar] = av.z; As[ac0 + 3][ar] = av.w;
        } else {
            As[ac0 + 0][ar] = 0.f; As[ac0 + 1][ar] = 0.f;
            As[ac0 + 2][ar] = 0.f; As[ac0 + 3][ar] = 0.f;
        }
        {
            float4 bv;
            ld4F(B, (size_t)(k0 + br) * N + col0 + bc0, bf, bv);
            Bs[br][bc0 + 0] = bv.x; Bs[br][bc0 + 1] = bv.y;
            Bs[br][bc0 + 2] = bv.z; Bs[br][bc0 + 3] = bv.w;
        }
        __syncthreads();
#pragma unroll
        for (int kk = 0; kk < BK; ++kk) {
            float a[4], b[4];
#pragma unroll
            for (int i = 0; i < 4; ++i) a[i] = As[kk][ty * 4 + i];
#pragma unroll
            for (int j = 0; j < 4; ++j) b[j] = Bs[kk][tx * 4 + j];
#pragma unroll
            for (int i = 0; i < 4; ++i)
#pragma unroll
                for (int j = 0; j < 4; ++j) acc[i][j] += a[i] * b[j];
        }
        __syncthreads();
    }
#pragma unroll
    for (int i = 0; i < 4; ++i) {
        int row = row0 + ty * 4 + i;
        if (row < M) {
#pragma unroll
            for (int j = 0; j < 4; ++j)
                st1(&C[(size_t)row * N + col0 + tx * 4 + j], acc[i][j]);
        }
    }
}

// ---------- gather-aggregate: out[i,:]=selfnorm[i]*h[i,:]+sum_e norm*h[src,:]+b ----------
template <typename TIN, typename TOUT>
__global__ __launch_bounds__(256) void k_agg(const TIN* __restrict__ h,
                                             const int* __restrict__ rowptr,
                                             const int* __restrict__ csr_src,
                                             const float* __restrict__ csr_norm,
                                             const float* __restrict__ selfnorm,
                                             const void* __restrict__ bias,
                                             const int* __restrict__ flagp,
                                             TOUT* __restrict__ out, int F, int relu) {
    bool bf = (*flagp != 0);
    int node = blockIdx.x;
    int tid = threadIdx.x;
    int e0 = rowptr[node], e1 = rowptr[node + 1];
    float sn = selfnorm[node];
    size_t nb = (size_t)node * F;
    float acc0 = sn * ld1(&h[nb + tid]);
    float acc1 = (F > 256) ? sn * ld1(&h[nb + tid + 256]) : 0.f;
    for (int j = e0; j < e1; ++j) {
        float w = csr_norm[j];
        size_t sb = (size_t)csr_src[j] * F;
        acc0 += w * ld1(&h[sb + tid]);
        if (F > 256) acc1 += w * ld1(&h[sb + tid + 256]);
    }
    acc0 += ldF(bias, tid, bf);
    if (relu) acc0 = fmaxf(acc0, 0.f);
    st1(&out[nb + tid], acc0);
    if (F > 256) {
        acc1 += ldF(bias, tid + 256, bf);
        if (relu) acc1 = fmaxf(acc1, 0.f);
        st1(&out[nb + tid + 256], acc1);
    }
}

// ---------- layer-5 GEMV: h5[i] = dot(A[i,0:256], W5) ----------
template <typename TA>
__global__ __launch_bounds__(256) void k_gemv(const TA* __restrict__ A,
                                              const void* __restrict__ W,
                                              const int* __restrict__ flagp,
                                              float* __restrict__ out, int K) {
    bool bf = (*flagp != 0);
    int wave = threadIdx.x >> 6, lane = threadIdx.x & 63;
    int row = blockIdx.x * 4 + wave;
    if (row >= N_NODES) return;
    float s = 0.f;
    for (int k = lane; k < K; k += 64) s += ld1(&A[(size_t)row * K + k]) * ldF(W, k, bf);
#pragma unroll
    for (int off = 32; off > 0; off >>= 1) s += __shfl_down(s, off);
    if (lane == 0) out[row] = s;
}

// ---------- final scalar aggregate, write output in harness dtype ----------
__global__ void k_final(const float* __restrict__ h5, const int* __restrict__ rowptr,
                        const int* __restrict__ csr_src, const float* __restrict__ csr_norm,
                        const float* __restrict__ selfnorm,
                        const void* __restrict__ b5, const int* __restrict__ flagp,
                        void* __restrict__ out) {
    bool bf = (*flagp != 0);
    int i = blockIdx.x * blockDim.x + threadIdx.x;
    if (i >= N_NODES) return;
    float acc = selfnorm[i] * h5[i];
    int e0 = rowptr[i], e1 = rowptr[i + 1];
    for (int j = e0; j < e1; ++j) acc += csr_norm[j] * h5[csr_src[j]];
    acc += ldF(b5, 0, bf);
    if (bf) ((unsigned short*)out)[i] = f2bf(acc);
    else    ((float*)out)[i] = acc;
}

// ---------- host-side: run the 5 layers with given internal dtypes ----------
template <typename TP, typename TH>
static void run_layers(TP* P, TH* H, float* h5,
                       const void* W1, const void* b1, const void* W2, const void* b2,
                       const void* W3, const void* b3, const void* W4, const void* b4,
                       const void* W5, const void* b5, const int* flagp,
                       const int* rowptr, const int* csr_src, const float* csr_norm,
                       const float* selfnorm, void* out, hipStream_t stream) {
    const int MB64 = (N_NODES + 63) / 64;  // 313
    const int NB = (N_NODES + 255) / 256;
    k_gemm<TP, TH><<<dim3(MB64, 8), 256, 0, stream>>>(P, W1, flagp, H, N_NODES, 512, 512);
    k_agg<TH, TP><<<N_NODES, 256, 0, stream>>>(H, rowptr, csr_src, csr_norm, selfnorm, b1, flagp, P, 512, 1);
    k_gemm<TP, TH><<<dim3(MB64, 8), 256, 0, stream>>>(P, W2, flagp, H, N_NODES, 512, 512);
    k_agg<TH, TP><<<N_NODES, 256, 0, stream>>>(H, rowptr, csr_src, csr_norm, selfnorm, b2, flagp, P, 512, 1);
    k_gemm<TP, TH><<<dim3(MB64, 8), 256, 0, stream>>>(P, W3, flagp, H, N_NODES, 512, 512);
    k_agg<TH, TP><<<N_NODES, 256, 0, stream>>>(H, rowptr, csr_src, csr_norm, selfnorm, b3, flagp, P, 512, 1);
    k_gemm<TP, TH><<<dim3(MB64, 4), 256, 0, stream>>>(P, W4, flagp, H, N_NODES, 512, 256);
    k_agg<TH, TP><<<N_NODES, 256, 0, stream>>>(H, rowptr, csr_src, csr_norm, selfnorm, b4, flagp, P, 256, 1);
    k_gemv<TP><<<(N_NODES + 3) / 4, 256, 0, stream>>>(P, W5, flagp, h5, 256);
    k_final<<<NB, 256, 0, stream>>>(h5, rowptr, csr_src, csr_norm, selfnorm, b5, flagp, out);
}

extern "C" void kernel_launch(void* const* d_in, const int* in_sizes, int n_in,
                              void* d_out, int out_size, void* d_ws, size_t ws_size,
                              hipStream_t stream) {
    const void* x  = d_in[0];
    const int*  ei = (const int*)d_in[1];
    const void* ea = d_in[2];
    const void* W1 = d_in[3];
    const void* b1 = d_in[4];
    const void* W2 = d_in[5];
    const void* b2 = d_in[6];
    const void* W3 = d_in[7];
    const void* b3 = d_in[8];
    const void* W4 = d_in[9];
    const void* b4 = d_in[10];
    const void* W5 = d_in[11];
    const void* b5 = d_in[12];

    // ---- workspace carve-up: small arrays first, big buffers sized to fit ----
    char* ws = (char*)d_ws;
    size_t off = 0;
    auto take = [&](size_t bytes) -> void* {
        off = (off + 255) & ~(size_t)255;
        void* p = ws + off;
        off += bytes;
        return p;
    };
    int*   flagp    = (int*)take(sizeof(int));
    float* deg      = (float*)take(N_NODES * sizeof(float));
    float* dinv     = (float*)take(N_NODES * sizeof(float));
    float* selfnorm = (float*)take(N_NODES * sizeof(float));
    float* h5       = (float*)take(N_NODES * sizeof(float));
    int*   counts   = (int*)take(N_NODES * sizeof(int));
    int*   fill     = (int*)take(N_NODES * sizeof(int));
    int*   rowptr   = (int*)take((N_NODES + 1) * sizeof(int));
    int*   src32    = (int*)take(N_EDGES * sizeof(int));
    int*   dst32    = (int*)take(N_EDGES * sizeof(int));
    int*   csr_src  = (int*)take(N_EDGES * sizeof(int));
    float* csr_norm = (float*)take(N_EDGES * sizeof(float));

    const size_t ACTF = (size_t)N_NODES * 512 * sizeof(float);          // 40.96 MB
    const size_t ACTH = (size_t)N_NODES * 512 * sizeof(unsigned short); // 20.48 MB
    size_t remain = (ws_size > off + 1024) ? ws_size - off - 1024 : 0;

    // zero what we accumulate into
    hipMemsetAsync(deg,    0, N_NODES * sizeof(float), stream);
    hipMemsetAsync(counts, 0, N_NODES * sizeof(int),   stream);
    hipMemsetAsync(fill,   0, N_NODES * sizeof(int),   stream);

    const int EB = (N_EDGES + 255) / 256;
    const int NB = (N_NODES + 255) / 256;

    k_detect<<<1, 64, 0, stream>>>((const unsigned int*)x, flagp);
    k_canon<<<EB, 256, 0, stream>>>(ei, src32, dst32);
    k_deg<<<EB, 256, 0, stream>>>(src32, dst32, ea, flagp, deg, counts);
    k_dinv<<<NB, 256, 0, stream>>>(deg, dinv, selfnorm);
    k_scan<<<1, 1024, 0, stream>>>(counts, rowptr);
    k_csr<<<EB, 256, 0, stream>>>(src32, dst32, ea, flagp, dinv, rowptr, fill, csr_src, csr_norm);

    const int nx = N_NODES * 512;
    if (remain >= 2 * ACTF + 512) {
        // tier A: fp32 activations both ways
        float* P = (float*)take(ACTF);
        float* H = (float*)take(ACTF);
        k_cast_in<float><<<(nx + 255) / 256, 256, 0, stream>>>(x, flagp, P, nx);
        run_layers<float, float>(P, H, h5, W1, b1, W2, b2, W3, b3, W4, b4, W5, b5, flagp,
                                 rowptr, csr_src, csr_norm, selfnorm, d_out, stream);
    } else if (remain >= ACTF + ACTH + 512) {
        // tier B: bf16 ping buffer, fp32 gemm-out
        unsigned short* P = (unsigned short*)take(ACTH);
        float* H = (float*)take(ACTF);
        k_cast_in<unsigned short><<<(nx + 255) / 256, 256, 0, stream>>>(x, flagp, P, nx);
        run_layers<unsigned short, float>(P, H, h5, W1, b1, W2, b2, W3, b3, W4, b4, W5, b5,
                                          flagp, rowptr, csr_src, csr_norm, selfnorm, d_out,
                                          stream);
    } else {
        // tier C: bf16 everywhere (min footprint ~48 MB)
        unsigned short* P = (unsigned short*)take(ACTH);
        unsigned short* H = (unsigned short*)take(ACTH);
        k_cast_in<unsigned short><<<(nx + 255) / 256, 256, 0, stream>>>(x, flagp, P, nx);
        run_layers<unsigned short, unsigned short>(P, H, h5, W1, b1, W2, b2, W3, b3, W4, b4,
                                                   W5, b5, flagp, rowptr, csr_src, csr_norm,
                                                   selfnorm, d_out, stream);
    }
}

// Round 4
// 914.297 us; speedup vs baseline: 1.4507x; 1.4507x over previous
//
#include <hip/hip_runtime.h>
#include <cstdint>
#include <cstddef>

#define N_NODES 20000
#define N_EDGES 400000

typedef __attribute__((ext_vector_type(8))) short bf16x8;
typedef __attribute__((ext_vector_type(4))) float f32x4;

// ---------- bf16 helpers (manual, bit-exact) ----------
__device__ __forceinline__ float bf2f(unsigned short u) {
    return __uint_as_float(((unsigned int)u) << 16);
}
__device__ __forceinline__ unsigned short f2bf(float f) {
    unsigned int x = __float_as_uint(f);
    unsigned int lsb = (x >> 16) & 1u;
    x += 0x7fffu + lsb;  // round-to-nearest-even
    return (unsigned short)(x >> 16);
}

// ---------- internal (templated) scalar load-store ----------
__device__ __forceinline__ float ld1(const float* p) { return *p; }
__device__ __forceinline__ float ld1(const unsigned short* p) { return bf2f(*p); }
__device__ __forceinline__ void st1(float* p, float v) { *p = v; }
__device__ __forceinline__ void st1(unsigned short* p, float v) { *p = f2bf(v); }

// ---------- flag-aware loads for harness float tensors (bf16 or fp32) ----------
__device__ __forceinline__ float ldF(const void* p, size_t i, bool bf) {
    return bf ? bf2f(((const unsigned short*)p)[i]) : ((const float*)p)[i];
}

// ---------- dtype detection: bf16 vs fp32, from x's bit patterns ----------
__global__ void k_detect(const unsigned int* __restrict__ xw, int* __restrict__ flag) {
    if (threadIdx.x != 0 || blockIdx.x != 0) return;
    int cnt = 0;
    for (int i = 0; i < 256; ++i) {
        unsigned short lo = (unsigned short)(xw[i] & 0xffffu);
        int e = (lo >> 7) & 0xff;
        if (e >= 110 && e <= 135) cnt++;
    }
    *flag = (cnt >= 128) ? 1 : 0;  // 1 = bf16
}

// ---------- canonicalize edge_index (handles int32 or raw-int64 layouts) ----------
__global__ void k_canon(const int* __restrict__ raw, int* __restrict__ src32,
                        int* __restrict__ dst32) {
    __shared__ int is64;
    if (threadIdx.x == 0) {
        int z = 1;
        for (int i = 1; i < 512; i += 2)
            if (raw[i] != 0) { z = 0; break; }
        is64 = z;
    }
    __syncthreads();
    int e = blockIdx.x * blockDim.x + threadIdx.x;
    if (e >= N_EDGES) return;
    if (is64) {
        src32[e] = raw[2 * e];
        dst32[e] = raw[2 * (N_EDGES + e)];
    } else {
        src32[e] = raw[e];
        dst32[e] = raw[N_EDGES + e];
    }
}

// ---------- precompute: degree + edge counts ----------
__global__ void k_deg(const int* __restrict__ src, const int* __restrict__ dst,
                      const void* __restrict__ ew, const int* __restrict__ flagp,
                      float* __restrict__ deg, int* __restrict__ counts) {
    bool bf = (*flagp != 0);
    int e = blockIdx.x * blockDim.x + threadIdx.x;
    if (e >= N_EDGES) return;
    int d = dst[e];
    atomicAdd(&deg[d], ldF(ew, e, bf));
    atomicAdd(&counts[d], 1);
}

__global__ void k_dinv(const float* __restrict__ deg, float* __restrict__ dinv,
                       float* __restrict__ selfnorm) {
    int i = blockIdx.x * blockDim.x + threadIdx.x;
    if (i >= N_NODES) return;
    float d = deg[i] + 1.0f;
    float r = rsqrtf(d);
    dinv[i] = r;
    selfnorm[i] = r * r;
}

// ---------- single-block exclusive scan of counts -> rowptr ----------
__global__ void k_scan(const int* __restrict__ counts, int* __restrict__ rowptr) {
    __shared__ int s[1024];
    const int T = 1024, CH = 20;
    int t = threadIdx.x;
    int base = t * CH;
    int local = 0;
    for (int j = 0; j < CH; ++j) {
        int idx = base + j;
        if (idx < N_NODES) local += counts[idx];
    }
    s[t] = local;
    __syncthreads();
    for (int off = 1; off < T; off <<= 1) {
        int v = (t >= off) ? s[t - off] : 0;
        __syncthreads();
        s[t] += v;
        __syncthreads();
    }
    int run = (t > 0) ? s[t - 1] : 0;
    for (int j = 0; j < CH; ++j) {
        int idx = base + j;
        if (idx < N_NODES) { rowptr[idx] = run; run += counts[idx]; }
    }
    if (t == T - 1) rowptr[N_NODES] = s[T - 1];
}

// ---------- scatter edges into CSR-by-dst with per-edge norm ----------
__global__ void k_csr(const int* __restrict__ src, const int* __restrict__ dst,
                      const void* __restrict__ ew, const int* __restrict__ flagp,
                      const float* __restrict__ dinv, const int* __restrict__ rowptr,
                      int* __restrict__ fill, int* __restrict__ csr_src,
                      float* __restrict__ csr_norm) {
    bool bf = (*flagp != 0);
    int e = blockIdx.x * blockDim.x + threadIdx.x;
    if (e >= N_EDGES) return;
    int s = src[e], d = dst[e];
    int p = rowptr[d] + atomicAdd(&fill[d], 1);
    csr_src[p] = s;
    csr_norm[p] = dinv[s] * ldF(ew, e, bf) * dinv[d];
}

// ---------- input cast -> bf16 ----------
__global__ void k_cast_in(const void* __restrict__ x, const int* __restrict__ flagp,
                          unsigned short* __restrict__ out, int n) {
    bool bf = (*flagp != 0);
    int i = blockIdx.x * blockDim.x + threadIdx.x;
    if (i < n) out[i] = f2bf(ldF(x, i, bf));
}

// ---------- pack weight W[K][N] (harness dtype) into MFMA B-fragment layout ----------
// Wp[(kb*nbt + nb)*64 + lane][j] ; lane = ((k%32)/8)*16 + n%16, j = k%8
__global__ void k_pack_w(const void* __restrict__ W, const int* __restrict__ flagp,
                         unsigned short* __restrict__ Wp, int K, int N, int nbl) {
    bool bf = (*flagp != 0);
    int idx = blockIdx.x * 256 + threadIdx.x;      // one per (kb, nb, lane)
    int total = (K >> 5) * (N >> 4) * 64;
    if (idx >= total) return;
    int lane = idx & 63;
    int blk = idx >> 6;                            // kb*nbt + nb
    int nb = blk & ((1 << nbl) - 1);
    int kb = blk >> nbl;
    int n = (nb << 4) + (lane & 15);
    int kbase = (kb << 5) + ((lane >> 4) << 3);
    unsigned short o[8];
#pragma unroll
    for (int j = 0; j < 8; ++j)
        o[j] = f2bf(ldF(W, (size_t)(kbase + j) * N + n, bf));
    *(uint4*)(&Wp[(size_t)idx * 8]) = *(const uint4*)o;
}

// ---------- MFMA bf16 GEMM: C[M,N](TC) = A[M,K](bf16) * Wp(packed bf16) ----------
// 256 threads (4 waves 2x2), tile 128x128, BK=32, 16x16x32 MFMA, fp32 accum.
template <typename TC>
__global__ __launch_bounds__(256) void k_gemm_mfma(const unsigned short* __restrict__ A,
                                                   const unsigned short* __restrict__ Bp,
                                                   TC* __restrict__ C,
                                                   int M, int K, int N) {
    const int AP = 40;  // A-tile row stride in elements (32 + 8 pad); 80 B, 16B-aligned
    __shared__ unsigned short As[128 * AP];   // 10240 B
    __shared__ unsigned short Bs[8 * 512];    // 8 nb * 64 lanes * 8 = 8192 B
    int tid = threadIdx.x;
    int lane = tid & 63;
    int wave = tid >> 6;
    int wr = wave >> 1, wc = wave & 1;
    int row0 = blockIdx.x * 128;
    int col0 = blockIdx.y * 128;
    int nbt = N >> 4;

    int q = lane >> 4;     // quad
    int mm = lane & 15;

    f32x4 acc[4][4] = {};  // [mb][nb]

    for (int kb = 0; kb < (K >> 5); ++kb) {
        // ---- stage A tile: 128 rows x 32 k (8 KB), 512 x 16B chunks
        const unsigned short* breg = Bp + (((size_t)kb * nbt + (col0 >> 4)) << 9);
#pragma unroll
        for (int i = 0; i < 2; ++i) {
            int c = tid + i * 256;
            int row = c >> 2, kq = c & 3;
            int grow = row0 + row;
            uint4 v = make_uint4(0u, 0u, 0u, 0u);
            if (grow < M)
                v = *(const uint4*)(&A[(size_t)grow * K + (kb << 5) + (kq << 3)]);
            *(uint4*)(&As[row * AP + (kq << 3)]) = v;
            // ---- stage B tile: straight copy of 8 KB packed region
            uint4 w = *(const uint4*)(&breg[(size_t)c * 8]);
            *(uint4*)(&Bs[(size_t)c * 8]) = w;
        }
        __syncthreads();
        bf16x8 af[4], bfr[4];
#pragma unroll
        for (int mb = 0; mb < 4; ++mb)
            af[mb] = *(const bf16x8*)(&As[(wr * 64 + mb * 16 + mm) * AP + q * 8]);
#pragma unroll
        for (int nb = 0; nb < 4; ++nb)
            bfr[nb] = *(const bf16x8*)(&Bs[((wc * 4 + nb) * 64 + lane) * 8]);
#pragma unroll
        for (int mb = 0; mb < 4; ++mb)
#pragma unroll
            for (int nb = 0; nb < 4; ++nb)
                acc[mb][nb] = __builtin_amdgcn_mfma_f32_16x16x32_bf16(
                    af[mb], bfr[nb], acc[mb][nb], 0, 0, 0);
        __syncthreads();
    }
    // ---- epilogue: C/D layout col=lane&15, row=quad*4+reg
#pragma unroll
    for (int mb = 0; mb < 4; ++mb) {
#pragma unroll
        for (int r = 0; r < 4; ++r) {
            int grow = row0 + wr * 64 + mb * 16 + q * 4 + r;
            if (grow < M) {
#pragma unroll
                for (int nb = 0; nb < 4; ++nb) {
                    int gcol = col0 + wc * 64 + nb * 16 + mm;
                    st1(&C[(size_t)grow * N + gcol], acc[mb][nb][r]);
                }
            }
        }
    }
}

// ---------- gather-aggregate: out[i,:]=selfnorm[i]*h[i,:]+sum_e norm*h[src,:]+b ----------
template <typename TIN, typename TOUT>
__global__ __launch_bounds__(256) void k_agg(const TIN* __restrict__ h,
                                             const int* __restrict__ rowptr,
                                             const int* __restrict__ csr_src,
                                             const float* __restrict__ csr_norm,
                                             const float* __restrict__ selfnorm,
                                             const void* __restrict__ bias,
                                             const int* __restrict__ flagp,
                                             TOUT* __restrict__ out, int F, int relu) {
    bool bf = (*flagp != 0);
    int node = blockIdx.x;
    int tid = threadIdx.x;
    int e0 = rowptr[node], e1 = rowptr[node + 1];
    float sn = selfnorm[node];
    size_t nb = (size_t)node * F;
    float acc0 = sn * ld1(&h[nb + tid]);
    float acc1 = (F > 256) ? sn * ld1(&h[nb + tid + 256]) : 0.f;
    for (int j = e0; j < e1; ++j) {
        float w = csr_norm[j];
        size_t sb = (size_t)csr_src[j] * F;
        acc0 += w * ld1(&h[sb + tid]);
        if (F > 256) acc1 += w * ld1(&h[sb + tid + 256]);
    }
    acc0 += ldF(bias, tid, bf);
    if (relu) acc0 = fmaxf(acc0, 0.f);
    st1(&out[nb + tid], acc0);
    if (F > 256) {
        acc1 += ldF(bias, tid + 256, bf);
        if (relu) acc1 = fmaxf(acc1, 0.f);
        st1(&out[nb + tid + 256], acc1);
    }
}

// ---------- layer-5 GEMV: h5[i] = dot(A[i,0:256], W5) ----------
__global__ __launch_bounds__(256) void k_gemv(const unsigned short* __restrict__ A,
                                              const void* __restrict__ W,
                                              const int* __restrict__ flagp,
                                              float* __restrict__ out, int K) {
    bool bf = (*flagp != 0);
    int wave = threadIdx.x >> 6, lane = threadIdx.x & 63;
    int row = blockIdx.x * 4 + wave;
    if (row >= N_NODES) return;
    float s = 0.f;
    for (int k = lane; k < K; k += 64) s += bf2f(A[(size_t)row * K + k]) * ldF(W, k, bf);
#pragma unroll
    for (int off = 32; off > 0; off >>= 1) s += __shfl_down(s, off);
    if (lane == 0) out[row] = s;
}

// ---------- final scalar aggregate, write output in harness dtype ----------
__global__ void k_final(const float* __restrict__ h5, const int* __restrict__ rowptr,
                        const int* __restrict__ csr_src, const float* __restrict__ csr_norm,
                        const float* __restrict__ selfnorm,
                        const void* __restrict__ b5, const int* __restrict__ flagp,
                        void* __restrict__ out) {
    bool bf = (*flagp != 0);
    int i = blockIdx.x * blockDim.x + threadIdx.x;
    if (i >= N_NODES) return;
    float acc = selfnorm[i] * h5[i];
    int e0 = rowptr[i], e1 = rowptr[i + 1];
    for (int j = e0; j < e1; ++j) acc += csr_norm[j] * h5[csr_src[j]];
    acc += ldF(b5, 0, bf);
    if (bf) ((unsigned short*)out)[i] = f2bf(acc);
    else    ((float*)out)[i] = acc;
}

// ---------- host-side: 5 layers; P = bf16 ping, H = TH gemm-out ----------
template <typename TH>
static void run_layers(unsigned short* P, TH* H, unsigned short* Wp, float* h5,
                       const void* W1, const void* b1, const void* W2, const void* b2,
                       const void* W3, const void* b3, const void* W4, const void* b4,
                       const void* W5, const void* b5, const int* flagp,
                       const int* rowptr, const int* csr_src, const float* csr_norm,
                       const float* selfnorm, void* out, hipStream_t stream) {
    const int MB128 = (N_NODES + 127) / 128;  // 157
    const int NB = (N_NODES + 255) / 256;
    const int PK512 = (16 * 32 * 64 + 255) / 256;  // pack blocks for 512x512
    const int PK256 = (16 * 16 * 64 + 255) / 256;  // pack blocks for 512x256

    k_pack_w<<<PK512, 256, 0, stream>>>(W1, flagp, Wp, 512, 512, 5);
    k_gemm_mfma<TH><<<dim3(MB128, 4), 256, 0, stream>>>(P, Wp, H, N_NODES, 512, 512);
    k_agg<TH, unsigned short><<<N_NODES, 256, 0, stream>>>(H, rowptr, csr_src, csr_norm, selfnorm, b1, flagp, P, 512, 1);

    k_pack_w<<<PK512, 256, 0, stream>>>(W2, flagp, Wp, 512, 512, 5);
    k_gemm_mfma<TH><<<dim3(MB128, 4), 256, 0, stream>>>(P, Wp, H, N_NODES, 512, 512);
    k_agg<TH, unsigned short><<<N_NODES, 256, 0, stream>>>(H, rowptr, csr_src, csr_norm, selfnorm, b2, flagp, P, 512, 1);

    k_pack_w<<<PK512, 256, 0, stream>>>(W3, flagp, Wp, 512, 512, 5);
    k_gemm_mfma<TH><<<dim3(MB128, 4), 256, 0, stream>>>(P, Wp, H, N_NODES, 512, 512);
    k_agg<TH, unsigned short><<<N_NODES, 256, 0, stream>>>(H, rowptr, csr_src, csr_norm, selfnorm, b3, flagp, P, 512, 1);

    k_pack_w<<<PK256, 256, 0, stream>>>(W4, flagp, Wp, 512, 256, 4);
    k_gemm_mfma<TH><<<dim3(MB128, 2), 256, 0, stream>>>(P, Wp, H, N_NODES, 512, 256);
    k_agg<TH, unsigned short><<<N_NODES, 256, 0, stream>>>(H, rowptr, csr_src, csr_norm, selfnorm, b4, flagp, P, 256, 1);

    k_gemv<<<(N_NODES + 3) / 4, 256, 0, stream>>>(P, W5, flagp, h5, 256);
    k_final<<<NB, 256, 0, stream>>>(h5, rowptr, csr_src, csr_norm, selfnorm, b5, flagp, out);
}

extern "C" void kernel_launch(void* const* d_in, const int* in_sizes, int n_in,
                              void* d_out, int out_size, void* d_ws, size_t ws_size,
                              hipStream_t stream) {
    const void* x  = d_in[0];
    const int*  ei = (const int*)d_in[1];
    const void* ea = d_in[2];
    const void* W1 = d_in[3];
    const void* b1 = d_in[4];
    const void* W2 = d_in[5];
    const void* b2 = d_in[6];
    const void* W3 = d_in[7];
    const void* b3 = d_in[8];
    const void* W4 = d_in[9];
    const void* b4 = d_in[10];
    const void* W5 = d_in[11];
    const void* b5 = d_in[12];

    char* ws = (char*)d_ws;
    size_t off = 0;
    auto take = [&](size_t bytes) -> void* {
        off = (off + 255) & ~(size_t)255;
        void* p = ws + off;
        off += bytes;
        return p;
    };
    int*   flagp    = (int*)take(sizeof(int));
    float* deg      = (float*)take(N_NODES * sizeof(float));
    float* dinv     = (float*)take(N_NODES * sizeof(float));
    float* selfnorm = (float*)take(N_NODES * sizeof(float));
    float* h5       = (float*)take(N_NODES * sizeof(float));
    int*   counts   = (int*)take(N_NODES * sizeof(int));
    int*   fill     = (int*)take(N_NODES * sizeof(int));
    int*   rowptr   = (int*)take((N_NODES + 1) * sizeof(int));
    int*   src32    = (int*)take(N_EDGES * sizeof(int));
    int*   dst32    = (int*)take(N_EDGES * sizeof(int));
    int*   csr_src  = (int*)take(N_EDGES * sizeof(int));
    float* csr_norm = (float*)take(N_EDGES * sizeof(float));
    unsigned short* Wp = (unsigned short*)take(512 * 512 * sizeof(unsigned short));
    unsigned short* P  = (unsigned short*)take((size_t)N_NODES * 512 * sizeof(unsigned short));

    const size_t ACTF = (size_t)N_NODES * 512 * sizeof(float);          // 40.96 MB
    const size_t ACTH = (size_t)N_NODES * 512 * sizeof(unsigned short); // 20.48 MB
    size_t remain = (ws_size > off + 1024) ? ws_size - off - 1024 : 0;

    hipMemsetAsync(deg,    0, N_NODES * sizeof(float), stream);
    hipMemsetAsync(counts, 0, N_NODES * sizeof(int),   stream);
    hipMemsetAsync(fill,   0, N_NODES * sizeof(int),   stream);

    const int EB = (N_EDGES + 255) / 256;
    const int NB = (N_NODES + 255) / 256;

    k_detect<<<1, 64, 0, stream>>>((const unsigned int*)x, flagp);
    k_canon<<<EB, 256, 0, stream>>>(ei, src32, dst32);
    k_deg<<<EB, 256, 0, stream>>>(src32, dst32, ea, flagp, deg, counts);
    k_dinv<<<NB, 256, 0, stream>>>(deg, dinv, selfnorm);
    k_scan<<<1, 1024, 0, stream>>>(counts, rowptr);
    k_csr<<<EB, 256, 0, stream>>>(src32, dst32, ea, flagp, dinv, rowptr, fill, csr_src, csr_norm);

    const int nx = N_NODES * 512;
    k_cast_in<<<(nx + 255) / 256, 256, 0, stream>>>(x, flagp, P, nx);

    if (remain >= ACTF) {
        // H in fp32 (preferred: agg reads full precision)
        float* H = (float*)take(ACTF);
        run_layers<float>(P, H, Wp, h5, W1, b1, W2, b2, W3, b3, W4, b4, W5, b5, flagp,
                          rowptr, csr_src, csr_norm, selfnorm, d_out, stream);
    } else {
        // H in bf16 (fallback, min footprint)
        unsigned short* H = (unsigned short*)take(ACTH);
        run_layers<unsigned short>(P, H, Wp, h5, W1, b1, W2, b2, W3, b3, W4, b4, W5, b5, flagp,
                                   rowptr, csr_src, csr_norm, selfnorm, d_out, stream);
    }
}

// Round 5
// 680.790 us; speedup vs baseline: 1.9483x; 1.3430x over previous
//
#include <hip/hip_runtime.h>
#include <cstdint>
#include <cstddef>

#define N_NODES 20000
#define N_EDGES 400000

typedef __attribute__((ext_vector_type(8))) short bf16x8;
typedef __attribute__((ext_vector_type(4))) float f32x4;

// ---------- bf16 helpers (manual, bit-exact) ----------
__device__ __forceinline__ float bf2f(unsigned short u) {
    return __uint_as_float(((unsigned int)u) << 16);
}
__device__ __forceinline__ unsigned short f2bf(float f) {
    unsigned int x = __float_as_uint(f);
    unsigned int lsb = (x >> 16) & 1u;
    x += 0x7fffu + lsb;  // round-to-nearest-even
    return (unsigned short)(x >> 16);
}

// ---------- flag-aware loads for harness float tensors (bf16 or fp32) ----------
__device__ __forceinline__ float ldF(const void* p, size_t i, bool bf) {
    return bf ? bf2f(((const unsigned short*)p)[i]) : ((const float*)p)[i];
}

// ---------- async global->LDS 16B copy (dest must be wave-uniform base + lane*16) ----------
__device__ __forceinline__ void gl2lds16(const unsigned short* g, unsigned short* l) {
    __builtin_amdgcn_global_load_lds(
        (const __attribute__((address_space(1))) void*)g,
        (__attribute__((address_space(3))) void*)l, 16, 0, 0);
}

// ---------- dtype detection: bf16 vs fp32, from x's bit patterns ----------
__global__ void k_detect(const unsigned int* __restrict__ xw, int* __restrict__ flag) {
    if (threadIdx.x != 0 || blockIdx.x != 0) return;
    int cnt = 0;
    for (int i = 0; i < 256; ++i) {
        unsigned short lo = (unsigned short)(xw[i] & 0xffffu);
        int e = (lo >> 7) & 0xff;
        if (e >= 110 && e <= 135) cnt++;
    }
    *flag = (cnt >= 128) ? 1 : 0;  // 1 = bf16
}

// ---------- canonicalize edge_index (handles int32 or raw-int64 layouts) ----------
__global__ void k_canon(const int* __restrict__ raw, int* __restrict__ src32,
                        int* __restrict__ dst32) {
    __shared__ int is64;
    if (threadIdx.x == 0) {
        int z = 1;
        for (int i = 1; i < 512; i += 2)
            if (raw[i] != 0) { z = 0; break; }
        is64 = z;
    }
    __syncthreads();
    int e = blockIdx.x * blockDim.x + threadIdx.x;
    if (e >= N_EDGES) return;
    if (is64) {
        src32[e] = raw[2 * e];
        dst32[e] = raw[2 * (N_EDGES + e)];
    } else {
        src32[e] = raw[e];
        dst32[e] = raw[N_EDGES + e];
    }
}

// ---------- precompute: degree + edge counts ----------
__global__ void k_deg(const int* __restrict__ src, const int* __restrict__ dst,
                      const void* __restrict__ ew, const int* __restrict__ flagp,
                      float* __restrict__ deg, int* __restrict__ counts) {
    bool bf = (*flagp != 0);
    int e = blockIdx.x * blockDim.x + threadIdx.x;
    if (e >= N_EDGES) return;
    int d = dst[e];
    atomicAdd(&deg[d], ldF(ew, e, bf));
    atomicAdd(&counts[d], 1);
}

__global__ void k_dinv(const float* __restrict__ deg, float* __restrict__ dinv,
                       float* __restrict__ selfnorm) {
    int i = blockIdx.x * blockDim.x + threadIdx.x;
    if (i >= N_NODES) return;
    float d = deg[i] + 1.0f;
    float r = rsqrtf(d);
    dinv[i] = r;
    selfnorm[i] = r * r;
}

// ---------- single-block exclusive scan of counts -> rowptr ----------
__global__ void k_scan(const int* __restrict__ counts, int* __restrict__ rowptr) {
    __shared__ int s[1024];
    const int T = 1024, CH = 20;
    int t = threadIdx.x;
    int base = t * CH;
    int local = 0;
    for (int j = 0; j < CH; ++j) {
        int idx = base + j;
        if (idx < N_NODES) local += counts[idx];
    }
    s[t] = local;
    __syncthreads();
    for (int off = 1; off < T; off <<= 1) {
        int v = (t >= off) ? s[t - off] : 0;
        __syncthreads();
        s[t] += v;
        __syncthreads();
    }
    int run = (t > 0) ? s[t - 1] : 0;
    for (int j = 0; j < CH; ++j) {
        int idx = base + j;
        if (idx < N_NODES) { rowptr[idx] = run; run += counts[idx]; }
    }
    if (t == T - 1) rowptr[N_NODES] = s[T - 1];
}

// ---------- scatter edges into CSR-by-dst with per-edge norm ----------
__global__ void k_csr(const int* __restrict__ src, const int* __restrict__ dst,
                      const void* __restrict__ ew, const int* __restrict__ flagp,
                      const float* __restrict__ dinv, const int* __restrict__ rowptr,
                      int* __restrict__ fill, int* __restrict__ csr_src,
                      float* __restrict__ csr_norm) {
    bool bf = (*flagp != 0);
    int e = blockIdx.x * blockDim.x + threadIdx.x;
    if (e >= N_EDGES) return;
    int s = src[e], d = dst[e];
    int p = rowptr[d] + atomicAdd(&fill[d], 1);
    csr_src[p] = s;
    csr_norm[p] = dinv[s] * ldF(ew, e, bf) * dinv[d];
}

// ---------- input cast -> bf16 ----------
__global__ void k_cast_in(const void* __restrict__ x, const int* __restrict__ flagp,
                          unsigned short* __restrict__ out, int n) {
    bool bf = (*flagp != 0);
    int i = blockIdx.x * blockDim.x + threadIdx.x;
    if (i < n) out[i] = f2bf(ldF(x, i, bf));
}

// ---------- pack weight W[K][N] (harness dtype) into MFMA B-fragment layout ----------
// Wp[(kb*nbt + nb)*64 + lane][j] ; lane = ((k%32)/8)*16 + n%16, j = k%8
__global__ void k_pack_w(const void* __restrict__ W, const int* __restrict__ flagp,
                         unsigned short* __restrict__ Wp, int K, int N, int nbl) {
    bool bf = (*flagp != 0);
    int idx = blockIdx.x * 256 + threadIdx.x;
    int total = (K >> 5) * (N >> 4) * 64;
    if (idx >= total) return;
    int lane = idx & 63;
    int blk = idx >> 6;
    int nb = blk & ((1 << nbl) - 1);
    int kb = blk >> nbl;
    int n = (nb << 4) + (lane & 15);
    int kbase = (kb << 5) + ((lane >> 4) << 3);
    unsigned short o[8];
#pragma unroll
    for (int j = 0; j < 8; ++j)
        o[j] = f2bf(ldF(W, (size_t)(kbase + j) * N + n, bf));
    *(uint4*)(&Wp[(size_t)idx * 8]) = *(const uint4*)o;
}

// ---------- MFMA bf16 GEMM: C[M,N](bf16) = A[M,K](bf16) * Wp(packed bf16) ----------
// 256 threads (4 waves 2x2), tile 128x128, BK=32, 16x16x32 MFMA, fp32 accum.
__global__ __launch_bounds__(256) void k_gemm_mfma(const unsigned short* __restrict__ A,
                                                   const unsigned short* __restrict__ Bp,
                                                   unsigned short* __restrict__ C,
                                                   int M, int K, int N) {
    const int AP = 40;  // A-tile row stride (32 + 8 pad) shorts; 80 B
    __shared__ __align__(16) unsigned short As[128 * AP];  // 10240 B
    __shared__ __align__(16) unsigned short Bs[8 * 512];   // 8192 B
    int tid = threadIdx.x;
    int lane = tid & 63;
    int wave = tid >> 6;
    int wr = wave >> 1, wc = wave & 1;
    int row0 = blockIdx.x * 128;
    int col0 = blockIdx.y * 128;
    int nbt = N >> 4;

    int q = lane >> 4;
    int mm = lane & 15;

    f32x4 acc[4][4] = {};

    for (int kb = 0; kb < (K >> 5); ++kb) {
        const unsigned short* breg = Bp + (((size_t)kb * nbt + (col0 >> 4)) << 9);
        // ---- B tile: async global->LDS, 2 x 256 lanes x 16B = 8 KB
        gl2lds16(breg + (size_t)tid * 8, &Bs[(size_t)tid * 8]);
        gl2lds16(breg + (size_t)(tid + 256) * 8, &Bs[(size_t)(tid + 256) * 8]);
        // ---- A tile: reg-staged (padded LDS rows)
#pragma unroll
        for (int i = 0; i < 2; ++i) {
            int c = tid + i * 256;
            int row = c >> 2, kq = c & 3;
            int grow = row0 + row;
            uint4 v = make_uint4(0u, 0u, 0u, 0u);
            if (grow < M)
                v = *(const uint4*)(&A[(size_t)grow * K + (kb << 5) + (kq << 3)]);
            *(uint4*)(&As[row * AP + (kq << 3)]) = v;
        }
        __syncthreads();
        bf16x8 af[4], bfr[4];
#pragma unroll
        for (int mb = 0; mb < 4; ++mb)
            af[mb] = *(const bf16x8*)(&As[(wr * 64 + mb * 16 + mm) * AP + q * 8]);
#pragma unroll
        for (int nb = 0; nb < 4; ++nb)
            bfr[nb] = *(const bf16x8*)(&Bs[((wc * 4 + nb) * 64 + lane) * 8]);
#pragma unroll
        for (int mb = 0; mb < 4; ++mb)
#pragma unroll
            for (int nb = 0; nb < 4; ++nb)
                acc[mb][nb] = __builtin_amdgcn_mfma_f32_16x16x32_bf16(
                    af[mb], bfr[nb], acc[mb][nb], 0, 0, 0);
        __syncthreads();
    }
    // ---- epilogue: C/D layout col=lane&15, row=quad*4+reg; store bf16
#pragma unroll
    for (int mb = 0; mb < 4; ++mb) {
#pragma unroll
        for (int r = 0; r < 4; ++r) {
            int grow = row0 + wr * 64 + mb * 16 + q * 4 + r;
            if (grow < M) {
#pragma unroll
                for (int nb = 0; nb < 4; ++nb) {
                    int gcol = col0 + wc * 64 + nb * 16 + mm;
                    C[(size_t)grow * N + gcol] = f2bf(acc[mb][nb][r]);
                }
            }
        }
    }
}

// ---------- gather-aggregate (bf16 h-table, uint-vectorized) ----------
// out[i,:] = relu(selfnorm[i]*h[i,:] + sum_e norm*h[src,:] + b), bf16 out
__global__ __launch_bounds__(256) void k_agg(const unsigned short* __restrict__ h,
                                             const int* __restrict__ rowptr,
                                             const int* __restrict__ csr_src,
                                             const float* __restrict__ csr_norm,
                                             const float* __restrict__ selfnorm,
                                             const void* __restrict__ bias,
                                             const int* __restrict__ flagp,
                                             unsigned short* __restrict__ out,
                                             int F, int relu) {
    int half = F >> 1;
    int tid = threadIdx.x;
    if (tid >= half) return;
    bool bf = (*flagp != 0);
    int node = blockIdx.x;
    int e0 = rowptr[node], e1 = rowptr[node + 1];
    float sn = selfnorm[node];
    const unsigned int* h2 = (const unsigned int*)h;
    unsigned int v = h2[(size_t)node * half + tid];
    float a0 = sn * bf2f((unsigned short)(v & 0xffffu));
    float a1 = sn * bf2f((unsigned short)(v >> 16));
    for (int j = e0; j < e1; ++j) {
        float w = csr_norm[j];
        unsigned int u = h2[(size_t)csr_src[j] * half + tid];
        a0 += w * bf2f((unsigned short)(u & 0xffffu));
        a1 += w * bf2f((unsigned short)(u >> 16));
    }
    a0 += ldF(bias, 2 * tid, bf);
    a1 += ldF(bias, 2 * tid + 1, bf);
    if (relu) { a0 = fmaxf(a0, 0.f); a1 = fmaxf(a1, 0.f); }
    ((unsigned int*)out)[(size_t)node * half + tid] =
        (unsigned int)f2bf(a0) | ((unsigned int)f2bf(a1) << 16);
}

// ---------- layer-5 GEMV: h5[i] = dot(A[i,0:256], W5) ----------
__global__ __launch_bounds__(256) void k_gemv(const unsigned short* __restrict__ A,
                                              const void* __restrict__ W,
                                              const int* __restrict__ flagp,
                                              float* __restrict__ out, int K) {
    bool bf = (*flagp != 0);
    int wave = threadIdx.x >> 6, lane = threadIdx.x & 63;
    int row = blockIdx.x * 4 + wave;
    if (row >= N_NODES) return;
    float s = 0.f;
    for (int k = lane; k < K; k += 64) s += bf2f(A[(size_t)row * K + k]) * ldF(W, k, bf);
#pragma unroll
    for (int off = 32; off > 0; off >>= 1) s += __shfl_down(s, off);
    if (lane == 0) out[row] = s;
}

// ---------- final scalar aggregate, write output in harness dtype ----------
__global__ void k_final(const float* __restrict__ h5, const int* __restrict__ rowptr,
                        const int* __restrict__ csr_src, const float* __restrict__ csr_norm,
                        const float* __restrict__ selfnorm,
                        const void* __restrict__ b5, const int* __restrict__ flagp,
                        void* __restrict__ out) {
    bool bf = (*flagp != 0);
    int i = blockIdx.x * blockDim.x + threadIdx.x;
    if (i >= N_NODES) return;
    float acc = selfnorm[i] * h5[i];
    int e0 = rowptr[i], e1 = rowptr[i + 1];
    for (int j = e0; j < e1; ++j) acc += csr_norm[j] * h5[csr_src[j]];
    acc += ldF(b5, 0, bf);
    if (bf) ((unsigned short*)out)[i] = f2bf(acc);
    else    ((float*)out)[i] = acc;
}

extern "C" void kernel_launch(void* const* d_in, const int* in_sizes, int n_in,
                              void* d_out, int out_size, void* d_ws, size_t ws_size,
                              hipStream_t stream) {
    const void* x  = d_in[0];
    const int*  ei = (const int*)d_in[1];
    const void* ea = d_in[2];
    const void* W1 = d_in[3];
    const void* b1 = d_in[4];
    const void* W2 = d_in[5];
    const void* b2 = d_in[6];
    const void* W3 = d_in[7];
    const void* b3 = d_in[8];
    const void* W4 = d_in[9];
    const void* b4 = d_in[10];
    const void* W5 = d_in[11];
    const void* b5 = d_in[12];

    char* ws = (char*)d_ws;
    size_t off = 0;
    auto take = [&](size_t bytes) -> void* {
        off = (off + 255) & ~(size_t)255;
        void* p = ws + off;
        off += bytes;
        return p;
    };
    int*   flagp    = (int*)take(sizeof(int));
    float* deg      = (float*)take(N_NODES * sizeof(float));
    float* dinv     = (float*)take(N_NODES * sizeof(float));
    float* selfnorm = (float*)take(N_NODES * sizeof(float));
    float* h5       = (float*)take(N_NODES * sizeof(float));
    int*   counts   = (int*)take(N_NODES * sizeof(int));
    int*   fill     = (int*)take(N_NODES * sizeof(int));
    int*   rowptr   = (int*)take((N_NODES + 1) * sizeof(int));
    int*   src32    = (int*)take(N_EDGES * sizeof(int));
    int*   dst32    = (int*)take(N_EDGES * sizeof(int));
    int*   csr_src  = (int*)take(N_EDGES * sizeof(int));
    float* csr_norm = (float*)take(N_EDGES * sizeof(float));
    unsigned short* Wp = (unsigned short*)take(512 * 512 * sizeof(unsigned short));
    unsigned short* P  = (unsigned short*)take((size_t)N_NODES * 512 * sizeof(unsigned short));
    unsigned short* H  = (unsigned short*)take((size_t)N_NODES * 512 * sizeof(unsigned short));

    hipMemsetAsync(deg,    0, N_NODES * sizeof(float), stream);
    hipMemsetAsync(counts, 0, N_NODES * sizeof(int),   stream);
    hipMemsetAsync(fill,   0, N_NODES * sizeof(int),   stream);

    const int EB = (N_EDGES + 255) / 256;
    const int NB = (N_NODES + 255) / 256;

    k_detect<<<1, 64, 0, stream>>>((const unsigned int*)x, flagp);
    k_canon<<<EB, 256, 0, stream>>>(ei, src32, dst32);
    k_deg<<<EB, 256, 0, stream>>>(src32, dst32, ea, flagp, deg, counts);
    k_dinv<<<NB, 256, 0, stream>>>(deg, dinv, selfnorm);
    k_scan<<<1, 1024, 0, stream>>>(counts, rowptr);
    k_csr<<<EB, 256, 0, stream>>>(src32, dst32, ea, flagp, dinv, rowptr, fill, csr_src, csr_norm);

    const int nx = N_NODES * 512;
    k_cast_in<<<(nx + 255) / 256, 256, 0, stream>>>(x, flagp, P, nx);

    const int MB128 = (N_NODES + 127) / 128;  // 157
    const int PK512 = (16 * 32 * 64 + 255) / 256;
    const int PK256 = (16 * 16 * 64 + 255) / 256;

    k_pack_w<<<PK512, 256, 0, stream>>>(W1, flagp, Wp, 512, 512, 5);
    k_gemm_mfma<<<dim3(MB128, 4), 256, 0, stream>>>(P, Wp, H, N_NODES, 512, 512);
    k_agg<<<N_NODES, 256, 0, stream>>>(H, rowptr, csr_src, csr_norm, selfnorm, b1, flagp, P, 512, 1);

    k_pack_w<<<PK512, 256, 0, stream>>>(W2, flagp, Wp, 512, 512, 5);
    k_gemm_mfma<<<dim3(MB128, 4), 256, 0, stream>>>(P, Wp, H, N_NODES, 512, 512);
    k_agg<<<N_NODES, 256, 0, stream>>>(H, rowptr, csr_src, csr_norm, selfnorm, b2, flagp, P, 512, 1);

    k_pack_w<<<PK512, 256, 0, stream>>>(W3, flagp, Wp, 512, 512, 5);
    k_gemm_mfma<<<dim3(MB128, 4), 256, 0, stream>>>(P, Wp, H, N_NODES, 512, 512);
    k_agg<<<N_NODES, 256, 0, stream>>>(H, rowptr, csr_src, csr_norm, selfnorm, b3, flagp, P, 512, 1);

    k_pack_w<<<PK256, 256, 0, stream>>>(W4, flagp, Wp, 512, 256, 4);
    k_gemm_mfma<<<dim3(MB128, 2), 256, 0, stream>>>(P, Wp, H, N_NODES, 512, 256);
    k_agg<<<N_NODES, 256, 0, stream>>>(H, rowptr, csr_src, csr_norm, selfnorm, b4, flagp, P, 256, 1);

    k_gemv<<<(N_NODES + 3) / 4, 256, 0, stream>>>(P, W5, flagp, h5, 256);
    k_final<<<NB, 256, 0, stream>>>(h5, rowptr, csr_src, csr_norm, selfnorm, b5, flagp,
                                    d_out);
}

// Round 6
// 551.891 us; speedup vs baseline: 2.4033x; 1.2336x over previous
//
#include <hip/hip_runtime.h>
#include <cstdint>
#include <cstddef>

#define N_NODES 20000
#define N_EDGES 400000

typedef __attribute__((ext_vector_type(8))) short bf16x8;
typedef __attribute__((ext_vector_type(4))) float f32x4;

// ---------- bf16 helpers (manual, bit-exact) ----------
__device__ __forceinline__ float bf2f(unsigned short u) {
    return __uint_as_float(((unsigned int)u) << 16);
}
__device__ __forceinline__ unsigned short f2bf(float f) {
    unsigned int x = __float_as_uint(f);
    unsigned int lsb = (x >> 16) & 1u;
    x += 0x7fffu + lsb;  // round-to-nearest-even
    return (unsigned short)(x >> 16);
}

// ---------- flag-aware loads for harness float tensors (bf16 or fp32) ----------
__device__ __forceinline__ float ldF(const void* p, size_t i, bool bf) {
    return bf ? bf2f(((const unsigned short*)p)[i]) : ((const float*)p)[i];
}

// ---------- async global->LDS 16B copy ----------
__device__ __forceinline__ void gl2lds16(const unsigned short* g, unsigned short* l) {
    __builtin_amdgcn_global_load_lds(
        (const __attribute__((address_space(1))) void*)g,
        (__attribute__((address_space(3))) void*)l, 16, 0, 0);
}

// ---------- dtype + int64 detection (once, 1 block) ----------
__global__ void k_detect(const unsigned int* __restrict__ xw, const int* __restrict__ raw,
                         int* __restrict__ flag) {
    if (blockIdx.x != 0 || threadIdx.x != 0) return;
    int cnt = 0;
    for (int i = 0; i < 256; ++i) {
        unsigned short lo = (unsigned short)(xw[i] & 0xffffu);
        int e = (lo >> 7) & 0xff;
        if (e >= 110 && e <= 135) cnt++;
    }
    flag[0] = (cnt >= 128) ? 1 : 0;  // 1 = float tensors are bf16
    int z = 1;
    for (int i = 1; i < 512; i += 2)
        if (raw[i] != 0) { z = 0; break; }
    flag[1] = z;                     // 1 = edge_index is raw int64
}

// ---------- canonicalize edge_index ----------
__global__ void k_canon(const int* __restrict__ raw, const int* __restrict__ flagp,
                        int* __restrict__ src32, int* __restrict__ dst32) {
    int is64 = flagp[1];
    int e = blockIdx.x * blockDim.x + threadIdx.x;
    if (e >= N_EDGES) return;
    if (is64) {
        src32[e] = raw[2 * e];
        dst32[e] = raw[2 * (N_EDGES + e)];
    } else {
        src32[e] = raw[e];
        dst32[e] = raw[N_EDGES + e];
    }
}

// ---------- precompute: degree + edge counts ----------
__global__ void k_deg(const int* __restrict__ src, const int* __restrict__ dst,
                      const void* __restrict__ ew, const int* __restrict__ flagp,
                      float* __restrict__ deg, int* __restrict__ counts) {
    bool bf = (*flagp != 0);
    int e = blockIdx.x * blockDim.x + threadIdx.x;
    if (e >= N_EDGES) return;
    int d = dst[e];
    atomicAdd(&deg[d], ldF(ew, e, bf));
    atomicAdd(&counts[d], 1);
}

__global__ void k_dinv(const float* __restrict__ deg, float* __restrict__ dinv,
                       float* __restrict__ selfnorm) {
    int i = blockIdx.x * blockDim.x + threadIdx.x;
    if (i >= N_NODES) return;
    float d = deg[i] + 1.0f;
    float r = rsqrtf(d);
    dinv[i] = r;
    selfnorm[i] = r * r;
}

// ---------- single-block exclusive scan of counts -> rowptr ----------
__global__ void k_scan(const int* __restrict__ counts, int* __restrict__ rowptr) {
    __shared__ int s[1024];
    const int T = 1024, CH = 20;
    int t = threadIdx.x;
    int base = t * CH;
    int local = 0;
    for (int j = 0; j < CH; ++j) {
        int idx = base + j;
        if (idx < N_NODES) local += counts[idx];
    }
    s[t] = local;
    __syncthreads();
    for (int off = 1; off < T; off <<= 1) {
        int v = (t >= off) ? s[t - off] : 0;
        __syncthreads();
        s[t] += v;
        __syncthreads();
    }
    int run = (t > 0) ? s[t - 1] : 0;
    for (int j = 0; j < CH; ++j) {
        int idx = base + j;
        if (idx < N_NODES) { rowptr[idx] = run; run += counts[idx]; }
    }
    if (t == T - 1) rowptr[N_NODES] = s[T - 1];
}

// ---------- scatter edges into CSR-by-dst with per-edge norm ----------
__global__ void k_csr(const int* __restrict__ src, const int* __restrict__ dst,
                      const void* __restrict__ ew, const int* __restrict__ flagp,
                      const float* __restrict__ dinv, const int* __restrict__ rowptr,
                      int* __restrict__ fill, int* __restrict__ csr_src,
                      float* __restrict__ csr_norm) {
    bool bf = (*flagp != 0);
    int e = blockIdx.x * blockDim.x + threadIdx.x;
    if (e >= N_EDGES) return;
    int s = src[e], d = dst[e];
    int p = rowptr[d] + atomicAdd(&fill[d], 1);
    csr_src[p] = s;
    csr_norm[p] = dinv[s] * ldF(ew, e, bf) * dinv[d];
}

// ---------- input cast -> bf16 ----------
__global__ void k_cast_in(const void* __restrict__ x, const int* __restrict__ flagp,
                          unsigned short* __restrict__ out, int n) {
    bool bf = (*flagp != 0);
    int i = blockIdx.x * blockDim.x + threadIdx.x;
    if (i < n) out[i] = f2bf(ldF(x, i, bf));
}

// ---------- cast harness float tensor -> fp32 ----------
__global__ void k_castf(const void* __restrict__ src, const int* __restrict__ flagp,
                        float* __restrict__ dst, int n) {
    bool bf = (*flagp != 0);
    int i = blockIdx.x * blockDim.x + threadIdx.x;
    if (i < n) dst[i] = ldF(src, i, bf);
}

// ---------- pack weight W[K][N] into MFMA B-fragment layout ----------
__global__ void k_pack_w(const void* __restrict__ W, const int* __restrict__ flagp,
                         unsigned short* __restrict__ Wp, int K, int N, int nbl) {
    bool bf = (*flagp != 0);
    int idx = blockIdx.x * 256 + threadIdx.x;
    int total = (K >> 5) * (N >> 4) * 64;
    if (idx >= total) return;
    int lane = idx & 63;
    int blk = idx >> 6;
    int nb = blk & ((1 << nbl) - 1);
    int kb = blk >> nbl;
    int n = (nb << 4) + (lane & 15);
    int kbase = (kb << 5) + ((lane >> 4) << 3);
    unsigned short o[8];
#pragma unroll
    for (int j = 0; j < 8; ++j)
        o[j] = f2bf(ldF(W, (size_t)(kbase + j) * N + n, bf));
    *(uint4*)(&Wp[(size_t)idx * 8]) = *(const uint4*)o;
}

// ---------- MFMA bf16 GEMM: C[M,N](bf16) = A[M,K](bf16) * Wp(packed) ----------
__global__ __launch_bounds__(256) void k_gemm_mfma(const unsigned short* __restrict__ A,
                                                   const unsigned short* __restrict__ Bp,
                                                   unsigned short* __restrict__ C,
                                                   int M, int K, int N) {
    const int AP = 40;
    __shared__ __align__(16) unsigned short As[128 * AP];
    __shared__ __align__(16) unsigned short Bs[8 * 512];
    int tid = threadIdx.x;
    int lane = tid & 63;
    int wave = tid >> 6;
    int wr = wave >> 1, wc = wave & 1;
    int row0 = blockIdx.x * 128;
    int col0 = blockIdx.y * 128;
    int nbt = N >> 4;
    int q = lane >> 4;
    int mm = lane & 15;

    f32x4 acc[4][4] = {};

    for (int kb = 0; kb < (K >> 5); ++kb) {
        const unsigned short* breg = Bp + (((size_t)kb * nbt + (col0 >> 4)) << 9);
        gl2lds16(breg + (size_t)tid * 8, &Bs[(size_t)tid * 8]);
        gl2lds16(breg + (size_t)(tid + 256) * 8, &Bs[(size_t)(tid + 256) * 8]);
#pragma unroll
        for (int i = 0; i < 2; ++i) {
            int c = tid + i * 256;
            int row = c >> 2, kq = c & 3;
            int grow = row0 + row;
            uint4 v = make_uint4(0u, 0u, 0u, 0u);
            if (grow < M)
                v = *(const uint4*)(&A[(size_t)grow * K + (kb << 5) + (kq << 3)]);
            *(uint4*)(&As[row * AP + (kq << 3)]) = v;
        }
        __syncthreads();
        bf16x8 af[4], bfr[4];
#pragma unroll
        for (int mb = 0; mb < 4; ++mb)
            af[mb] = *(const bf16x8*)(&As[(wr * 64 + mb * 16 + mm) * AP + q * 8]);
#pragma unroll
        for (int nb = 0; nb < 4; ++nb)
            bfr[nb] = *(const bf16x8*)(&Bs[((wc * 4 + nb) * 64 + lane) * 8]);
#pragma unroll
        for (int mb = 0; mb < 4; ++mb)
#pragma unroll
            for (int nb = 0; nb < 4; ++nb)
                acc[mb][nb] = __builtin_amdgcn_mfma_f32_16x16x32_bf16(
                    af[mb], bfr[nb], acc[mb][nb], 0, 0, 0);
        __syncthreads();
    }
#pragma unroll
    for (int mb = 0; mb < 4; ++mb) {
#pragma unroll
        for (int r = 0; r < 4; ++r) {
            int grow = row0 + wr * 64 + mb * 16 + q * 4 + r;
            if (grow < M) {
#pragma unroll
                for (int nb = 0; nb < 4; ++nb) {
                    int gcol = col0 + wc * 64 + nb * 16 + mm;
                    C[(size_t)grow * N + gcol] = f2bf(acc[mb][nb][r]);
                }
            }
        }
    }
}

// ---------- wave-per-node gather-aggregate ----------
// F features; FPL = F/64 features per lane (8 -> uint4 loads, 4 -> uint2).
// out[i,:] = relu(selfnorm[i]*h[i,:] + sum_e norm*h[src,:] + biasf), bf16 out.
template <int F, int FPL>
__global__ __launch_bounds__(256) void k_agg_w(const unsigned short* __restrict__ h,
                                               const int* __restrict__ rowptr,
                                               const int* __restrict__ csr_src,
                                               const float* __restrict__ csr_norm,
                                               const float* __restrict__ selfnorm,
                                               const float* __restrict__ biasf,
                                               unsigned short* __restrict__ out,
                                               int relu) {
    constexpr int W = FPL / 2;  // dwords per lane
    int lane = threadIdx.x & 63;
    int wave = threadIdx.x >> 6;
    int node = blockIdx.x * 4 + wave;
    if (node >= N_NODES) return;
    int e0 = rowptr[node], e1 = rowptr[node + 1];
    float sn = selfnorm[node];

    float acc[FPL];
    {
        const unsigned int* p = (const unsigned int*)(h + (size_t)node * F) + lane * W;
        unsigned int u[W];
        if constexpr (W == 4) {
            uint4 v = *(const uint4*)p; u[0]=v.x; u[1]=v.y; u[2]=v.z; u[3]=v.w;
        } else {
            uint2 v = *(const uint2*)p; u[0]=v.x; u[1]=v.y;
        }
#pragma unroll
        for (int k = 0; k < W; ++k) {
            acc[2*k]   = sn * bf2f((unsigned short)(u[k] & 0xffffu));
            acc[2*k+1] = sn * bf2f((unsigned short)(u[k] >> 16));
        }
    }
    int j = e0;
    for (; j + 1 < e1; j += 2) {
        int s0 = csr_src[j], s1 = csr_src[j + 1];
        float w0 = csr_norm[j], w1 = csr_norm[j + 1];
        const unsigned int* p0 = (const unsigned int*)(h + (size_t)s0 * F) + lane * W;
        const unsigned int* p1 = (const unsigned int*)(h + (size_t)s1 * F) + lane * W;
        unsigned int u0[W], u1[W];
        if constexpr (W == 4) {
            uint4 a = *(const uint4*)p0; u0[0]=a.x; u0[1]=a.y; u0[2]=a.z; u0[3]=a.w;
            uint4 b = *(const uint4*)p1; u1[0]=b.x; u1[1]=b.y; u1[2]=b.z; u1[3]=b.w;
        } else {
            uint2 a = *(const uint2*)p0; u0[0]=a.x; u0[1]=a.y;
            uint2 b = *(const uint2*)p1; u1[0]=b.x; u1[1]=b.y;
        }
#pragma unroll
        for (int k = 0; k < W; ++k) {
            acc[2*k]   = fmaf(bf2f((unsigned short)(u0[k] & 0xffffu)), w0, acc[2*k]);
            acc[2*k+1] = fmaf(bf2f((unsigned short)(u0[k] >> 16)),     w0, acc[2*k+1]);
            acc[2*k]   = fmaf(bf2f((unsigned short)(u1[k] & 0xffffu)), w1, acc[2*k]);
            acc[2*k+1] = fmaf(bf2f((unsigned short)(u1[k] >> 16)),     w1, acc[2*k+1]);
        }
    }
    if (j < e1) {
        int s0 = csr_src[j];
        float w0 = csr_norm[j];
        const unsigned int* p0 = (const unsigned int*)(h + (size_t)s0 * F) + lane * W;
        unsigned int u0[W];
        if constexpr (W == 4) {
            uint4 a = *(const uint4*)p0; u0[0]=a.x; u0[1]=a.y; u0[2]=a.z; u0[3]=a.w;
        } else {
            uint2 a = *(const uint2*)p0; u0[0]=a.x; u0[1]=a.y;
        }
#pragma unroll
        for (int k = 0; k < W; ++k) {
            acc[2*k]   = fmaf(bf2f((unsigned short)(u0[k] & 0xffffu)), w0, acc[2*k]);
            acc[2*k+1] = fmaf(bf2f((unsigned short)(u0[k] >> 16)),     w0, acc[2*k+1]);
        }
    }
    {
        const float* bp = biasf + lane * FPL;
#pragma unroll
        for (int k = 0; k < FPL; ++k) acc[k] += bp[k];
        if (relu) {
#pragma unroll
            for (int k = 0; k < FPL; ++k) acc[k] = fmaxf(acc[k], 0.f);
        }
        unsigned int o[W];
#pragma unroll
        for (int k = 0; k < W; ++k)
            o[k] = (unsigned int)f2bf(acc[2*k]) | ((unsigned int)f2bf(acc[2*k+1]) << 16);
        unsigned int* q = (unsigned int*)(out + (size_t)node * F) + lane * W;
        if constexpr (W == 4) { *(uint4*)q = make_uint4(o[0], o[1], o[2], o[3]); }
        else                  { *(uint2*)q = make_uint2(o[0], o[1]); }
    }
}

// ---------- layer-5 GEMV: h5[i] = dot(A[i,0:256], W5) ----------
__global__ __launch_bounds__(256) void k_gemv(const unsigned short* __restrict__ A,
                                              const void* __restrict__ W,
                                              const int* __restrict__ flagp,
                                              float* __restrict__ out, int K) {
    bool bf = (*flagp != 0);
    int wave = threadIdx.x >> 6, lane = threadIdx.x & 63;
    int row = blockIdx.x * 4 + wave;
    if (row >= N_NODES) return;
    float s = 0.f;
    for (int k = lane; k < K; k += 64) s += bf2f(A[(size_t)row * K + k]) * ldF(W, k, bf);
#pragma unroll
    for (int off = 32; off > 0; off >>= 1) s += __shfl_down(s, off);
    if (lane == 0) out[row] = s;
}

// ---------- final scalar aggregate, write output in harness dtype ----------
__global__ void k_final(const float* __restrict__ h5, const int* __restrict__ rowptr,
                        const int* __restrict__ csr_src, const float* __restrict__ csr_norm,
                        const float* __restrict__ selfnorm,
                        const void* __restrict__ b5, const int* __restrict__ flagp,
                        void* __restrict__ out) {
    bool bf = (*flagp != 0);
    int i = blockIdx.x * blockDim.x + threadIdx.x;
    if (i >= N_NODES) return;
    float acc = selfnorm[i] * h5[i];
    int e0 = rowptr[i], e1 = rowptr[i + 1];
    for (int j = e0; j < e1; ++j) acc += csr_norm[j] * h5[csr_src[j]];
    acc += ldF(b5, 0, bf);
    if (bf) ((unsigned short*)out)[i] = f2bf(acc);
    else    ((float*)out)[i] = acc;
}

extern "C" void kernel_launch(void* const* d_in, const int* in_sizes, int n_in,
                              void* d_out, int out_size, void* d_ws, size_t ws_size,
                              hipStream_t stream) {
    const void* x  = d_in[0];
    const int*  ei = (const int*)d_in[1];
    const void* ea = d_in[2];
    const void* W1 = d_in[3];
    const void* b1 = d_in[4];
    const void* W2 = d_in[5];
    const void* b2 = d_in[6];
    const void* W3 = d_in[7];
    const void* b3 = d_in[8];
    const void* W4 = d_in[9];
    const void* b4 = d_in[10];
    const void* W5 = d_in[11];
    const void* b5 = d_in[12];

    char* ws = (char*)d_ws;
    size_t off = 0;
    auto take = [&](size_t bytes) -> void* {
        off = (off + 255) & ~(size_t)255;
        void* p = ws + off;
        off += bytes;
        return p;
    };
    int*   flagp    = (int*)take(2 * sizeof(int));
    float* deg      = (float*)take(N_NODES * sizeof(float));
    float* dinv     = (float*)take(N_NODES * sizeof(float));
    float* selfnorm = (float*)take(N_NODES * sizeof(float));
    float* h5       = (float*)take(N_NODES * sizeof(float));
    float* biasf    = (float*)take(512 * sizeof(float));
    int*   counts   = (int*)take(N_NODES * sizeof(int));
    int*   fill     = (int*)take(N_NODES * sizeof(int));
    int*   rowptr   = (int*)take((N_NODES + 1) * sizeof(int));
    int*   src32    = (int*)take(N_EDGES * sizeof(int));
    int*   dst32    = (int*)take(N_EDGES * sizeof(int));
    int*   csr_src  = (int*)take(N_EDGES * sizeof(int));
    float* csr_norm = (float*)take(N_EDGES * sizeof(float));
    unsigned short* Wp = (unsigned short*)take(512 * 512 * sizeof(unsigned short));
    unsigned short* P  = (unsigned short*)take((size_t)N_NODES * 512 * sizeof(unsigned short));
    unsigned short* H  = (unsigned short*)take((size_t)N_NODES * 512 * sizeof(unsigned short));

    hipMemsetAsync(deg,    0, N_NODES * sizeof(float), stream);
    hipMemsetAsync(counts, 0, N_NODES * sizeof(int),   stream);
    hipMemsetAsync(fill,   0, N_NODES * sizeof(int),   stream);

    const int EB = (N_EDGES + 255) / 256;
    const int NB = (N_NODES + 255) / 256;
    const int AGB = (N_NODES + 3) / 4;  // wave-per-node blocks

    k_detect<<<1, 64, 0, stream>>>((const unsigned int*)x, ei, flagp);
    k_canon<<<EB, 256, 0, stream>>>(ei, flagp, src32, dst32);
    k_deg<<<EB, 256, 0, stream>>>(src32, dst32, ea, flagp, deg, counts);
    k_dinv<<<NB, 256, 0, stream>>>(deg, dinv, selfnorm);
    k_scan<<<1, 1024, 0, stream>>>(counts, rowptr);
    k_csr<<<EB, 256, 0, stream>>>(src32, dst32, ea, flagp, dinv, rowptr, fill, csr_src, csr_norm);

    const int nx = N_NODES * 512;
    k_cast_in<<<(nx + 255) / 256, 256, 0, stream>>>(x, flagp, P, nx);

    const int MB128 = (N_NODES + 127) / 128;  // 157
    const int PK512 = (16 * 32 * 64 + 255) / 256;
    const int PK256 = (16 * 16 * 64 + 255) / 256;

    k_pack_w<<<PK512, 256, 0, stream>>>(W1, flagp, Wp, 512, 512, 5);
    k_castf<<<2, 256, 0, stream>>>(b1, flagp, biasf, 512);
    k_gemm_mfma<<<dim3(MB128, 4), 256, 0, stream>>>(P, Wp, H, N_NODES, 512, 512);
    k_agg_w<512, 8><<<AGB, 256, 0, stream>>>(H, rowptr, csr_src, csr_norm, selfnorm, biasf, P, 1);

    k_pack_w<<<PK512, 256, 0, stream>>>(W2, flagp, Wp, 512, 512, 5);
    k_castf<<<2, 256, 0, stream>>>(b2, flagp, biasf, 512);
    k_gemm_mfma<<<dim3(MB128, 4), 256, 0, stream>>>(P, Wp, H, N_NODES, 512, 512);
    k_agg_w<512, 8><<<AGB, 256, 0, stream>>>(H, rowptr, csr_src, csr_norm, selfnorm, biasf, P, 1);

    k_pack_w<<<PK512, 256, 0, stream>>>(W3, flagp, Wp, 512, 512, 5);
    k_castf<<<2, 256, 0, stream>>>(b3, flagp, biasf, 512);
    k_gemm_mfma<<<dim3(MB128, 4), 256, 0, stream>>>(P, Wp, H, N_NODES, 512, 512);
    k_agg_w<512, 8><<<AGB, 256, 0, stream>>>(H, rowptr, csr_src, csr_norm, selfnorm, biasf, P, 1);

    k_pack_w<<<PK256, 256, 0, stream>>>(W4, flagp, Wp, 512, 256, 4);
    k_castf<<<1, 256, 0, stream>>>(b4, flagp, biasf, 256);
    k_gemm_mfma<<<dim3(MB128, 2), 256, 0, stream>>>(P, Wp, H, N_NODES, 512, 256);
    k_agg_w<256, 4><<<AGB, 256, 0, stream>>>(H, rowptr, csr_src, csr_norm, selfnorm, biasf, P, 1);

    k_gemv<<<(N_NODES + 3) / 4, 256, 0, stream>>>(P, W5, flagp, h5, 256);
    k_final<<<NB, 256, 0, stream>>>(h5, rowptr, csr_src, csr_norm, selfnorm, b5, flagp,
                                    d_out);
}

// Round 7
// 516.384 us; speedup vs baseline: 2.5686x; 1.0688x over previous
//
#include <hip/hip_runtime.h>
#include <cstdint>
#include <cstddef>

#define N_NODES 20000
#define N_EDGES 400000

typedef __attribute__((ext_vector_type(8))) short bf16x8;
typedef __attribute__((ext_vector_type(4))) float f32x4;

// ---------- bf16 helpers (manual, bit-exact) ----------
__device__ __forceinline__ float bf2f(unsigned short u) {
    return __uint_as_float(((unsigned int)u) << 16);
}
__device__ __forceinline__ unsigned short f2bf(float f) {
    unsigned int x = __float_as_uint(f);
    unsigned int lsb = (x >> 16) & 1u;
    x += 0x7fffu + lsb;  // round-to-nearest-even
    return (unsigned short)(x >> 16);
}

// ---------- flag-aware loads for harness float tensors (bf16 or fp32) ----------
__device__ __forceinline__ float ldF(const void* p, size_t i, bool bf) {
    return bf ? bf2f(((const unsigned short*)p)[i]) : ((const float*)p)[i];
}

// ---------- async global->LDS 16B copy ----------
__device__ __forceinline__ void gl2lds16(const unsigned short* g, unsigned short* l) {
    __builtin_amdgcn_global_load_lds(
        (const __attribute__((address_space(1))) void*)g,
        (__attribute__((address_space(3))) void*)l, 16, 0, 0);
}

// ---------- dtype + int64 detection (one wave, lane-parallel) ----------
__global__ void k_detect(const unsigned int* __restrict__ xw, const int* __restrict__ raw,
                         int* __restrict__ flag) {
    int lane = threadIdx.x;
    int cnt = 0, nz = 0;
    for (int i = lane; i < 256; i += 64) {
        unsigned short lo = (unsigned short)(xw[i] & 0xffffu);
        int e = (lo >> 7) & 0xff;
        if (e >= 110 && e <= 135) cnt++;
    }
    for (int i = 2 * lane + 1; i < 512; i += 128)
        if (raw[i] != 0) nz++;
#pragma unroll
    for (int off = 32; off > 0; off >>= 1) {
        cnt += __shfl_down(cnt, off);
        nz  += __shfl_down(nz, off);
    }
    if (lane == 0) {
        flag[0] = (cnt >= 128) ? 1 : 0;  // 1 = float tensors are bf16
        flag[1] = (nz == 0) ? 1 : 0;     // 1 = edge_index is raw int64
    }
}

// ---------- canonicalize edge_index + degree + counts (fused) ----------
__global__ void k_canon_deg(const int* __restrict__ raw, const void* __restrict__ ew,
                            const int* __restrict__ flagp,
                            int* __restrict__ src32, int* __restrict__ dst32,
                            float* __restrict__ deg, int* __restrict__ counts) {
    bool bf = (flagp[0] != 0);
    int is64 = flagp[1];
    int e = blockIdx.x * blockDim.x + threadIdx.x;
    if (e >= N_EDGES) return;
    int s, d;
    if (is64) { s = raw[2 * e]; d = raw[2 * (N_EDGES + e)]; }
    else      { s = raw[e];     d = raw[N_EDGES + e]; }
    src32[e] = s;
    dst32[e] = d;
    atomicAdd(&deg[d], ldF(ew, e, bf));
    atomicAdd(&counts[d], 1);
}

__global__ void k_dinv(const float* __restrict__ deg, float* __restrict__ dinv,
                       float* __restrict__ selfnorm) {
    int i = blockIdx.x * blockDim.x + threadIdx.x;
    if (i >= N_NODES) return;
    float d = deg[i] + 1.0f;
    float r = rsqrtf(d);
    dinv[i] = r;
    selfnorm[i] = r * r;
}

// ---------- single-block exclusive scan of counts -> rowptr ----------
__global__ void k_scan(const int* __restrict__ counts, int* __restrict__ rowptr) {
    __shared__ int s[1024];
    const int T = 1024, CH = 20;
    int t = threadIdx.x;
    int base = t * CH;
    int local = 0;
    for (int j = 0; j < CH; ++j) {
        int idx = base + j;
        if (idx < N_NODES) local += counts[idx];
    }
    s[t] = local;
    __syncthreads();
    for (int off = 1; off < T; off <<= 1) {
        int v = (t >= off) ? s[t - off] : 0;
        __syncthreads();
        s[t] += v;
        __syncthreads();
    }
    int run = (t > 0) ? s[t - 1] : 0;
    for (int j = 0; j < CH; ++j) {
        int idx = base + j;
        if (idx < N_NODES) { rowptr[idx] = run; run += counts[idx]; }
    }
    if (t == T - 1) rowptr[N_NODES] = s[T - 1];
}

// ---------- scatter edges into CSR-by-dst with per-edge norm ----------
__global__ void k_csr(const int* __restrict__ src, const int* __restrict__ dst,
                      const void* __restrict__ ew, const int* __restrict__ flagp,
                      const float* __restrict__ dinv, const int* __restrict__ rowptr,
                      int* __restrict__ fill, int* __restrict__ csr_src,
                      float* __restrict__ csr_norm) {
    bool bf = (*flagp != 0);
    int e = blockIdx.x * blockDim.x + threadIdx.x;
    if (e >= N_EDGES) return;
    int s = src[e], d = dst[e];
    int p = rowptr[d] + atomicAdd(&fill[d], 1);
    csr_src[p] = s;
    csr_norm[p] = dinv[s] * ldF(ew, e, bf) * dinv[d];
}

// ---------- input cast -> bf16, float4-vectorized ----------
__global__ void k_cast_in(const void* __restrict__ x, const int* __restrict__ flagp,
                          unsigned short* __restrict__ out, int n4) {
    bool bf = (*flagp != 0);
    int i = blockIdx.x * blockDim.x + threadIdx.x;
    if (i >= n4) return;
    if (bf) {
        ((uint2*)out)[i] = ((const uint2*)x)[i];
    } else {
        float4 v = ((const float4*)x)[i];
        unsigned int lo = (unsigned int)f2bf(v.x) | ((unsigned int)f2bf(v.y) << 16);
        unsigned int hi = (unsigned int)f2bf(v.z) | ((unsigned int)f2bf(v.w) << 16);
        ((uint2*)out)[i] = make_uint2(lo, hi);
    }
}

// ---------- pack ALL weights into MFMA B-fragment layout (one launch) ----------
// layout idx ranges: L1 [0,32768) L2 [32768,65536) L3 [65536,98304) L4 [98304,114688)
__global__ void k_pack_all(const void* __restrict__ W1, const void* __restrict__ W2,
                           const void* __restrict__ W3, const void* __restrict__ W4,
                           const int* __restrict__ flagp, unsigned short* __restrict__ Wp) {
    bool bf = (*flagp != 0);
    int gidx = blockIdx.x * 256 + threadIdx.x;
    if (gidx >= 114688) return;
    const void* W;
    int idx = gidx, N, nbl;
    if (gidx < 32768)      { W = W1; N = 512; nbl = 5; }
    else if (gidx < 65536) { W = W2; N = 512; nbl = 5; idx -= 32768; }
    else if (gidx < 98304) { W = W3; N = 512; nbl = 5; idx -= 65536; }
    else                   { W = W4; N = 256; nbl = 4; idx -= 98304; }
    int lane = idx & 63;
    int blk = idx >> 6;
    int nb = blk & ((1 << nbl) - 1);
    int kb = blk >> nbl;
    int n = (nb << 4) + (lane & 15);
    int kbase = (kb << 5) + ((lane >> 4) << 3);
    unsigned short o[8];
#pragma unroll
    for (int j = 0; j < 8; ++j)
        o[j] = f2bf(ldF(W, (size_t)(kbase + j) * N + n, bf));
    *(uint4*)(&Wp[(size_t)gidx * 8]) = *(const uint4*)o;
}

// ---------- cast all biases -> fp32 (one launch); biasf[L*512 + r] ----------
__global__ void k_castb(const void* __restrict__ b1, const void* __restrict__ b2,
                        const void* __restrict__ b3, const void* __restrict__ b4,
                        const int* __restrict__ flagp, float* __restrict__ biasf) {
    bool bf = (*flagp != 0);
    int i = blockIdx.x * blockDim.x + threadIdx.x;
    if (i >= 2048) return;
    int L = i >> 9, r = i & 511;
    if (L == 3 && r >= 256) return;
    const void* b = (L == 0) ? b1 : (L == 1) ? b2 : (L == 2) ? b3 : b4;
    biasf[i] = ldF(b, r, bf);
}

// ---------- MFMA bf16 GEMM: C[M,N](bf16) = A[M,K](bf16) * Wp(packed) ----------
__global__ __launch_bounds__(256) void k_gemm_mfma(const unsigned short* __restrict__ A,
                                                   const unsigned short* __restrict__ Bp,
                                                   unsigned short* __restrict__ C,
                                                   int M, int K, int N) {
    const int AP = 40;
    __shared__ __align__(16) unsigned short As[128 * AP];
    __shared__ __align__(16) unsigned short Bs[8 * 512];
    int tid = threadIdx.x;
    int lane = tid & 63;
    int wave = tid >> 6;
    int wr = wave >> 1, wc = wave & 1;
    int row0 = blockIdx.x * 128;
    int col0 = blockIdx.y * 128;
    int nbt = N >> 4;
    int q = lane >> 4;
    int mm = lane & 15;

    f32x4 acc[4][4] = {};

    for (int kb = 0; kb < (K >> 5); ++kb) {
        const unsigned short* breg = Bp + (((size_t)kb * nbt + (col0 >> 4)) << 9);
        gl2lds16(breg + (size_t)tid * 8, &Bs[(size_t)tid * 8]);
        gl2lds16(breg + (size_t)(tid + 256) * 8, &Bs[(size_t)(tid + 256) * 8]);
#pragma unroll
        for (int i = 0; i < 2; ++i) {
            int c = tid + i * 256;
            int row = c >> 2, kq = c & 3;
            int grow = row0 + row;
            uint4 v = make_uint4(0u, 0u, 0u, 0u);
            if (grow < M)
                v = *(const uint4*)(&A[(size_t)grow * K + (kb << 5) + (kq << 3)]);
            *(uint4*)(&As[row * AP + (kq << 3)]) = v;
        }
        __syncthreads();
        bf16x8 af[4], bfr[4];
#pragma unroll
        for (int mb = 0; mb < 4; ++mb)
            af[mb] = *(const bf16x8*)(&As[(wr * 64 + mb * 16 + mm) * AP + q * 8]);
#pragma unroll
        for (int nb = 0; nb < 4; ++nb)
            bfr[nb] = *(const bf16x8*)(&Bs[((wc * 4 + nb) * 64 + lane) * 8]);
#pragma unroll
        for (int mb = 0; mb < 4; ++mb)
#pragma unroll
            for (int nb = 0; nb < 4; ++nb)
                acc[mb][nb] = __builtin_amdgcn_mfma_f32_16x16x32_bf16(
                    af[mb], bfr[nb], acc[mb][nb], 0, 0, 0);
        __syncthreads();
    }
#pragma unroll
    for (int mb = 0; mb < 4; ++mb) {
#pragma unroll
        for (int r = 0; r < 4; ++r) {
            int grow = row0 + wr * 64 + mb * 16 + q * 4 + r;
            if (grow < M) {
#pragma unroll
                for (int nb = 0; nb < 4; ++nb) {
                    int gcol = col0 + wc * 64 + nb * 16 + mm;
                    C[(size_t)grow * N + gcol] = f2bf(acc[mb][nb][r]);
                }
            }
        }
    }
}

// ---------- row-load + fma helpers for the gather ----------
template <int W>
__device__ __forceinline__ void ldrow(const unsigned short* h, size_t row, int F, int lane,
                                      unsigned int* u) {
    const unsigned int* p = (const unsigned int*)(h + row * F) + lane * W;
    if constexpr (W == 4) {
        uint4 v = *(const uint4*)p; u[0] = v.x; u[1] = v.y; u[2] = v.z; u[3] = v.w;
    } else {
        uint2 v = *(const uint2*)p; u[0] = v.x; u[1] = v.y;
    }
}
template <int W>
__device__ __forceinline__ void fmarow(const unsigned int* u, float w, float* acc) {
#pragma unroll
    for (int k = 0; k < W; ++k) {
        acc[2 * k]     = fmaf(bf2f((unsigned short)(u[k] & 0xffffu)), w, acc[2 * k]);
        acc[2 * k + 1] = fmaf(bf2f((unsigned short)(u[k] >> 16)),     w, acc[2 * k + 1]);
    }
}

// ---------- wave-per-node gather-aggregate, 4-edge unroll ----------
template <int F, int FPL>
__global__ __launch_bounds__(256) void k_agg_w(const unsigned short* __restrict__ h,
                                               const int* __restrict__ rowptr,
                                               const int* __restrict__ csr_src,
                                               const float* __restrict__ csr_norm,
                                               const float* __restrict__ selfnorm,
                                               const float* __restrict__ biasf,
                                               unsigned short* __restrict__ out,
                                               int relu) {
    constexpr int W = FPL / 2;
    int lane = threadIdx.x & 63;
    int wave = threadIdx.x >> 6;
    int node = blockIdx.x * 4 + wave;
    if (node >= N_NODES) return;
    int e0 = rowptr[node], e1 = rowptr[node + 1];
    float sn = selfnorm[node];

    float acc[FPL];
    {
        unsigned int u[W];
        ldrow<W>(h, (size_t)node, F, lane, u);
#pragma unroll
        for (int k = 0; k < W; ++k) {
            acc[2 * k]     = sn * bf2f((unsigned short)(u[k] & 0xffffu));
            acc[2 * k + 1] = sn * bf2f((unsigned short)(u[k] >> 16));
        }
    }
    int j = e0;
    for (; j + 3 < e1; j += 4) {
        int s0 = csr_src[j], s1 = csr_src[j + 1], s2 = csr_src[j + 2], s3 = csr_src[j + 3];
        float w0 = csr_norm[j], w1 = csr_norm[j + 1], w2 = csr_norm[j + 2], w3 = csr_norm[j + 3];
        unsigned int u0[W], u1[W], u2[W], u3[W];
        ldrow<W>(h, (size_t)s0, F, lane, u0);
        ldrow<W>(h, (size_t)s1, F, lane, u1);
        ldrow<W>(h, (size_t)s2, F, lane, u2);
        ldrow<W>(h, (size_t)s3, F, lane, u3);
        fmarow<W>(u0, w0, acc);
        fmarow<W>(u1, w1, acc);
        fmarow<W>(u2, w2, acc);
        fmarow<W>(u3, w3, acc);
    }
    for (; j < e1; ++j) {
        int s0 = csr_src[j];
        float w0 = csr_norm[j];
        unsigned int u0[W];
        ldrow<W>(h, (size_t)s0, F, lane, u0);
        fmarow<W>(u0, w0, acc);
    }
    {
        const float* bp = biasf + lane * FPL;
#pragma unroll
        for (int k = 0; k < FPL; ++k) acc[k] += bp[k];
        if (relu) {
#pragma unroll
            for (int k = 0; k < FPL; ++k) acc[k] = fmaxf(acc[k], 0.f);
        }
        unsigned int o[W];
#pragma unroll
        for (int k = 0; k < W; ++k)
            o[k] = (unsigned int)f2bf(acc[2 * k]) | ((unsigned int)f2bf(acc[2 * k + 1]) << 16);
        unsigned int* q = (unsigned int*)(out + (size_t)node * F) + lane * W;
        if constexpr (W == 4) { *(uint4*)q = make_uint4(o[0], o[1], o[2], o[3]); }
        else                  { *(uint2*)q = make_uint2(o[0], o[1]); }
    }
}

// ---------- layer-5 GEMV: h5[i] = dot(A[i,0:256], W5) ----------
__global__ __launch_bounds__(256) void k_gemv(const unsigned short* __restrict__ A,
                                              const void* __restrict__ W,
                                              const int* __restrict__ flagp,
                                              float* __restrict__ out, int K) {
    bool bf = (*flagp != 0);
    int wave = threadIdx.x >> 6, lane = threadIdx.x & 63;
    int row = blockIdx.x * 4 + wave;
    if (row >= N_NODES) return;
    float s = 0.f;
    for (int k = lane; k < K; k += 64) s += bf2f(A[(size_t)row * K + k]) * ldF(W, k, bf);
#pragma unroll
    for (int off = 32; off > 0; off >>= 1) s += __shfl_down(s, off);
    if (lane == 0) out[row] = s;
}

// ---------- final scalar aggregate, write output in harness dtype ----------
__global__ void k_final(const float* __restrict__ h5, const int* __restrict__ rowptr,
                        const int* __restrict__ csr_src, const float* __restrict__ csr_norm,
                        const float* __restrict__ selfnorm,
                        const void* __restrict__ b5, const int* __restrict__ flagp,
                        void* __restrict__ out) {
    bool bf = (*flagp != 0);
    int i = blockIdx.x * blockDim.x + threadIdx.x;
    if (i >= N_NODES) return;
    float acc = selfnorm[i] * h5[i];
    int e0 = rowptr[i], e1 = rowptr[i + 1];
    for (int j = e0; j < e1; ++j) acc += csr_norm[j] * h5[csr_src[j]];
    acc += ldF(b5, 0, bf);
    if (bf) ((unsigned short*)out)[i] = f2bf(acc);
    else    ((float*)out)[i] = acc;
}

extern "C" void kernel_launch(void* const* d_in, const int* in_sizes, int n_in,
                              void* d_out, int out_size, void* d_ws, size_t ws_size,
                              hipStream_t stream) {
    const void* x  = d_in[0];
    const int*  ei = (const int*)d_in[1];
    const void* ea = d_in[2];
    const void* W1 = d_in[3];
    const void* b1 = d_in[4];
    const void* W2 = d_in[5];
    const void* b2 = d_in[6];
    const void* W3 = d_in[7];
    const void* b3 = d_in[8];
    const void* W4 = d_in[9];
    const void* b4 = d_in[10];
    const void* W5 = d_in[11];
    const void* b5 = d_in[12];

    char* ws = (char*)d_ws;
    size_t off = 0;
    auto take = [&](size_t bytes) -> void* {
        off = (off + 255) & ~(size_t)255;
        void* p = ws + off;
        off += bytes;
        return p;
    };
    int*   flagp    = (int*)take(2 * sizeof(int));
    float* deg      = (float*)take(N_NODES * sizeof(float));
    float* dinv     = (float*)take(N_NODES * sizeof(float));
    float* selfnorm = (float*)take(N_NODES * sizeof(float));
    float* h5       = (float*)take(N_NODES * sizeof(float));
    float* biasf    = (float*)take(4 * 512 * sizeof(float));
    int*   counts   = (int*)take(N_NODES * sizeof(int));
    int*   fill     = (int*)take(N_NODES * sizeof(int));
    int*   rowptr   = (int*)take((N_NODES + 1) * sizeof(int));
    int*   src32    = (int*)take(N_EDGES * sizeof(int));
    int*   dst32    = (int*)take(N_EDGES * sizeof(int));
    int*   csr_src  = (int*)take(N_EDGES * sizeof(int));
    float* csr_norm = (float*)take(N_EDGES * sizeof(float));
    unsigned short* Wp = (unsigned short*)take((size_t)114688 * 8 * sizeof(unsigned short));
    unsigned short* P  = (unsigned short*)take((size_t)N_NODES * 512 * sizeof(unsigned short));
    unsigned short* H  = (unsigned short*)take((size_t)N_NODES * 512 * sizeof(unsigned short));

    hipMemsetAsync(deg,    0, N_NODES * sizeof(float), stream);
    hipMemsetAsync(counts, 0, N_NODES * sizeof(int),   stream);
    hipMemsetAsync(fill,   0, N_NODES * sizeof(int),   stream);

    const int EB = (N_EDGES + 255) / 256;
    const int NB = (N_NODES + 255) / 256;
    const int AGB = (N_NODES + 3) / 4;

    k_detect<<<1, 64, 0, stream>>>((const unsigned int*)x, ei, flagp);
    k_canon_deg<<<EB, 256, 0, stream>>>(ei, ea, flagp, src32, dst32, deg, counts);
    k_dinv<<<NB, 256, 0, stream>>>(deg, dinv, selfnorm);
    k_scan<<<1, 1024, 0, stream>>>(counts, rowptr);
    k_csr<<<EB, 256, 0, stream>>>(src32, dst32, ea, flagp, dinv, rowptr, fill, csr_src, csr_norm);

    const int n4 = (N_NODES * 512) / 4;
    k_cast_in<<<(n4 + 255) / 256, 256, 0, stream>>>(x, flagp, P, n4);
    k_pack_all<<<(114688 + 255) / 256, 256, 0, stream>>>(W1, W2, W3, W4, flagp, Wp);
    k_castb<<<8, 256, 0, stream>>>(b1, b2, b3, b4, flagp, biasf);

    const int MB128 = (N_NODES + 127) / 128;  // 157

    k_gemm_mfma<<<dim3(MB128, 4), 256, 0, stream>>>(P, Wp, H, N_NODES, 512, 512);
    k_agg_w<512, 8><<<AGB, 256, 0, stream>>>(H, rowptr, csr_src, csr_norm, selfnorm,
                                             biasf, P, 1);
    k_gemm_mfma<<<dim3(MB128, 4), 256, 0, stream>>>(P, Wp + (size_t)32768 * 8, H,
                                                    N_NODES, 512, 512);
    k_agg_w<512, 8><<<AGB, 256, 0, stream>>>(H, rowptr, csr_src, csr_norm, selfnorm,
                                             biasf + 512, P, 1);
    k_gemm_mfma<<<dim3(MB128, 4), 256, 0, stream>>>(P, Wp + (size_t)65536 * 8, H,
                                                    N_NODES, 512, 512);
    k_agg_w<512, 8><<<AGB, 256, 0, stream>>>(H, rowptr, csr_src, csr_norm, selfnorm,
                                             biasf + 1024, P, 1);
    k_gemm_mfma<<<dim3(MB128, 2), 256, 0, stream>>>(P, Wp + (size_t)98304 * 8, H,
                                                    N_NODES, 512, 256);
    k_agg_w<256, 4><<<AGB, 256, 0, stream>>>(H, rowptr, csr_src, csr_norm, selfnorm,
                                             biasf + 1536, P, 1);

    k_gemv<<<(N_NODES + 3) / 4, 256, 0, stream>>>(P, W5, flagp, h5, 256);
    k_final<<<NB, 256, 0, stream>>>(h5, rowptr, csr_src, csr_norm, selfnorm, b5, flagp,
                                    d_out);
}